// Round 1
// baseline (794.038 us; speedup 1.0000x reference)
//
#include <hip/hip_runtime.h>
#include <hip/hip_bf16.h>

#define IN_F 512
#define OH   512   // OUT*H
#define NH   8     // heads

// ---------------------------------------------------------------------------
// GEMM: Z[n, j] = sum_i X[n,i] * W[j,i] + bias[j]     (f32, vector ALU)
// 128x128 tile, BK=16, 256 threads, 8x8 micro-tile per thread.
// ---------------------------------------------------------------------------
#define BM 128
#define BN 128
#define BK 16

__global__ __launch_bounds__(256) void k_gemm(const float* __restrict__ X,
                                              const float* __restrict__ W,
                                              const float* __restrict__ bias,
                                              float* __restrict__ Z, int N) {
  __shared__ float As[BK][BM];
  __shared__ float Bs[BK][BN];
  int tid = threadIdx.x;
  int tx = tid & 15, ty = tid >> 4;
  int n0 = blockIdx.y * BM;
  int j0 = blockIdx.x * BN;

  float acc[8][8];
#pragma unroll
  for (int i = 0; i < 8; i++)
#pragma unroll
    for (int j = 0; j < 8; j++) acc[i][j] = 0.f;

  for (int kt = 0; kt < IN_F; kt += BK) {
#pragma unroll
    for (int f = tid; f < (BM * BK / 4); f += 256) {
      int r  = f >> 2;          // row within tile 0..127
      int kc = (f & 3) << 2;    // k-offset 0,4,8,12
      int n = n0 + r;
      float4 va = make_float4(0.f, 0.f, 0.f, 0.f);
      if (n < N) va = *(const float4*)&X[(size_t)n * IN_F + kt + kc];
      As[kc + 0][r] = va.x; As[kc + 1][r] = va.y;
      As[kc + 2][r] = va.z; As[kc + 3][r] = va.w;
      float4 vb = *(const float4*)&W[(size_t)(j0 + r) * IN_F + kt + kc];
      Bs[kc + 0][r] = vb.x; Bs[kc + 1][r] = vb.y;
      Bs[kc + 2][r] = vb.z; Bs[kc + 3][r] = vb.w;
    }
    __syncthreads();
#pragma unroll
    for (int kk = 0; kk < BK; kk++) {
      float a[8], b[8];
      *(float4*)&a[0] = *(const float4*)&As[kk][ty * 8];
      *(float4*)&a[4] = *(const float4*)&As[kk][ty * 8 + 4];
      *(float4*)&b[0] = *(const float4*)&Bs[kk][tx * 8];
      *(float4*)&b[4] = *(const float4*)&Bs[kk][tx * 8 + 4];
#pragma unroll
      for (int i = 0; i < 8; i++)
#pragma unroll
        for (int j = 0; j < 8; j++) acc[i][j] = fmaf(a[i], b[j], acc[i][j]);
    }
    __syncthreads();
  }

  float bv[8];
#pragma unroll
  for (int j = 0; j < 8; j++) bv[j] = bias[j0 + tx * 8 + j];
#pragma unroll
  for (int i = 0; i < 8; i++) {
    int n = n0 + ty * 8 + i;
    if (n < N) {
      float4 o0 = make_float4(acc[i][0] + bv[0], acc[i][1] + bv[1],
                              acc[i][2] + bv[2], acc[i][3] + bv[3]);
      float4 o1 = make_float4(acc[i][4] + bv[4], acc[i][5] + bv[5],
                              acc[i][6] + bv[6], acc[i][7] + bv[7]);
      *(float4*)&Z[(size_t)n * OH + j0 + tx * 8]     = o0;
      *(float4*)&Z[(size_t)n * OH + j0 + tx * 8 + 4] = o1;
    }
  }
}

// ---------------------------------------------------------------------------
// e_l[n,h] = sum_o Z[n,o,h]*a_l[o,h];  e_r likewise.  One wave per node:
// lane l owns o=l (8 contiguous floats of the Z row), butterfly-reduce.
// ---------------------------------------------------------------------------
__global__ __launch_bounds__(256) void k_elr(const float* __restrict__ Z,
                                             const float* __restrict__ al,
                                             const float* __restrict__ ar,
                                             float* __restrict__ el,
                                             float* __restrict__ er, int N) {
  int wid = threadIdx.x >> 6, lane = threadIdx.x & 63;
  int n = blockIdx.x * 4 + wid;
  if (n >= N) return;
  const float4* zp = (const float4*)(Z + (size_t)n * OH + lane * 8);
  float4 z0 = zp[0], z1 = zp[1];
  const float4* ap = (const float4*)(al + lane * 8);
  float4 a0 = ap[0], a1 = ap[1];
  const float4* bp = (const float4*)(ar + lane * 8);
  float4 b0 = bp[0], b1 = bp[1];

  float pl[8] = {z0.x * a0.x, z0.y * a0.y, z0.z * a0.z, z0.w * a0.w,
                 z1.x * a1.x, z1.y * a1.y, z1.z * a1.z, z1.w * a1.w};
  float pr[8] = {z0.x * b0.x, z0.y * b0.y, z0.z * b0.z, z0.w * b0.w,
                 z1.x * b1.x, z1.y * b1.y, z1.z * b1.z, z1.w * b1.w};
#pragma unroll
  for (int s = 1; s < 64; s <<= 1) {
#pragma unroll
    for (int h = 0; h < 8; h++) {
      pl[h] += __shfl_xor(pl[h], s);
      pr[h] += __shfl_xor(pr[h], s);
    }
  }
  if (lane == 0) {
    float4* e0 = (float4*)(el + (size_t)n * NH);
    e0[0] = make_float4(pl[0], pl[1], pl[2], pl[3]);
    e0[1] = make_float4(pl[4], pl[5], pl[6], pl[7]);
    float4* e1 = (float4*)(er + (size_t)n * NH);
    e1[0] = make_float4(pr[0], pr[1], pr[2], pr[3]);
    e1[1] = make_float4(pr[4], pr[5], pr[6], pr[7]);
  }
}

// ---------------------------------------------------------------------------
// CSR build
// ---------------------------------------------------------------------------
__global__ void k_zero(int* __restrict__ p, int n) {
  int i = blockIdx.x * blockDim.x + threadIdx.x;
  if (i < n) p[i] = 0;
}

__global__ void k_hist(const int* __restrict__ row, int* __restrict__ deg, int E) {
  int e = blockIdx.x * blockDim.x + threadIdx.x;
  if (e < E) atomicAdd(&deg[row[e]], 1);
}

#define SCAN_B 1024
__global__ __launch_bounds__(SCAN_B) void k_scan1(const int* __restrict__ deg,
                                                  int* __restrict__ off,
                                                  int* __restrict__ sums, int N) {
  __shared__ int s[SCAN_B];
  int tid = threadIdx.x;
  int g = blockIdx.x * SCAN_B + tid;
  int v = (g < N) ? deg[g] : 0;
  s[tid] = v;
  __syncthreads();
  for (int o = 1; o < SCAN_B; o <<= 1) {
    int t = (tid >= o) ? s[tid - o] : 0;
    __syncthreads();
    s[tid] += t;
    __syncthreads();
  }
  if (g < N) off[g] = s[tid] - v;  // exclusive prefix within block
  if (tid == SCAN_B - 1) sums[blockIdx.x] = s[tid];
}

__global__ void k_scan2(const int* __restrict__ sums, int* __restrict__ boff,
                        int* __restrict__ off, int nb, int N, int E) {
  if (threadIdx.x == 0 && blockIdx.x == 0) {
    int run = 0;
    for (int b = 0; b < nb; ++b) { boff[b] = run; run += sums[b]; }
    off[N] = E;
  }
}

__global__ __launch_bounds__(SCAN_B) void k_scan3(int* __restrict__ off,
                                                  int* __restrict__ cursor,
                                                  const int* __restrict__ boff, int N) {
  int g = blockIdx.x * SCAN_B + threadIdx.x;
  if (g < N) {
    int v = off[g] + boff[blockIdx.x];
    off[g] = v;
    cursor[g] = v;
  }
}

__global__ void k_fill(const int* __restrict__ row, const int* __restrict__ col,
                       int* __restrict__ cursor, int* __restrict__ colS, int E) {
  int e = blockIdx.x * blockDim.x + threadIdx.x;
  if (e < E) {
    int r = row[e];
    int p = atomicAdd(&cursor[r], 1);
    colS[p] = col[e];
  }
}

// ---------------------------------------------------------------------------
// Aggregation: one wave per destination row i.
// pass 1: m[h] = max over its edges of lrelu(el[i,h]+er[c,h])
// pass 2: den[h] += exp(e-m);  acc[jj] += p[jj] * Z[c, lane*8+jj]
// out[i, lane*8+jj] = acc/den     (h == jj since j = o*8+h)
// ---------------------------------------------------------------------------
__global__ __launch_bounds__(256) void k_agg(const float* __restrict__ Z,
                                             const float* __restrict__ el,
                                             const float* __restrict__ er,
                                             const int* __restrict__ off,
                                             const int* __restrict__ colS,
                                             float* __restrict__ out, int N) {
  int wid = threadIdx.x >> 6, lane = threadIdx.x & 63;
  int i = blockIdx.x * 4 + wid;
  if (i >= N) return;
  int s = off[i], t = off[i + 1];

  float eli[8];
  {
    const float4* e4 = (const float4*)(el + (size_t)i * NH);
    float4 a = e4[0], b = e4[1];
    eli[0] = a.x; eli[1] = a.y; eli[2] = a.z; eli[3] = a.w;
    eli[4] = b.x; eli[5] = b.y; eli[6] = b.z; eli[7] = b.w;
  }

  float m[8];
#pragma unroll
  for (int h = 0; h < 8; h++) m[h] = -1e30f;

  for (int p = s; p < t; p++) {
    int c = colS[p];
    const float4* e4 = (const float4*)(er + (size_t)c * NH);
    float4 ea = e4[0], eb = e4[1];
    float ev[8] = {ea.x, ea.y, ea.z, ea.w, eb.x, eb.y, eb.z, eb.w};
#pragma unroll
    for (int h = 0; h < 8; h++) {
      float eh = eli[h] + ev[h];
      eh = (eh > 0.f) ? eh : 0.01f * eh;
      m[h] = fmaxf(m[h], eh);
    }
  }

  float den[8], acc[8];
#pragma unroll
  for (int h = 0; h < 8; h++) { den[h] = 0.f; acc[h] = 0.f; }

  for (int p = s; p < t; p++) {
    int c = colS[p];
    const float4* e4 = (const float4*)(er + (size_t)c * NH);
    float4 ea = e4[0], eb = e4[1];
    float ev[8] = {ea.x, ea.y, ea.z, ea.w, eb.x, eb.y, eb.z, eb.w};
    float pr[8];
#pragma unroll
    for (int h = 0; h < 8; h++) {
      float eh = eli[h] + ev[h];
      eh = (eh > 0.f) ? eh : 0.01f * eh;
      pr[h] = __expf(eh - m[h]);
      den[h] += pr[h];
    }
    const float4* zp = (const float4*)(Z + (size_t)c * OH + lane * 8);
    float4 z0 = zp[0], z1 = zp[1];
    acc[0] = fmaf(pr[0], z0.x, acc[0]);
    acc[1] = fmaf(pr[1], z0.y, acc[1]);
    acc[2] = fmaf(pr[2], z0.z, acc[2]);
    acc[3] = fmaf(pr[3], z0.w, acc[3]);
    acc[4] = fmaf(pr[4], z1.x, acc[4]);
    acc[5] = fmaf(pr[5], z1.y, acc[5]);
    acc[6] = fmaf(pr[6], z1.z, acc[6]);
    acc[7] = fmaf(pr[7], z1.w, acc[7]);
  }

  float4 o0, o1;
  if (t > s) {
    o0 = make_float4(acc[0] / den[0], acc[1] / den[1], acc[2] / den[2], acc[3] / den[3]);
    o1 = make_float4(acc[4] / den[4], acc[5] / den[5], acc[6] / den[6], acc[7] / den[7]);
  } else {
    o0 = make_float4(0.f, 0.f, 0.f, 0.f);
    o1 = o0;
  }
  *(float4*)(out + (size_t)i * OH + lane * 8)     = o0;
  *(float4*)(out + (size_t)i * OH + lane * 8 + 4) = o1;
}

// ---------------------------------------------------------------------------
extern "C" void kernel_launch(void* const* d_in, const int* in_sizes, int n_in,
                              void* d_out, int out_size, void* d_ws, size_t ws_size,
                              hipStream_t stream) {
  const float* X    = (const float*)d_in[0];
  const float* W    = (const float*)d_in[1];
  const float* bias = (const float*)d_in[2];
  const float* a_l  = (const float*)d_in[3];
  const float* a_r  = (const float*)d_in[4];
  const int*   row  = (const int*)d_in[5];
  const int*   col  = (const int*)d_in[6];
  float* out = (float*)d_out;

  const int N = in_sizes[0] / IN_F;   // 50000
  const int E = in_sizes[5];          // 850000

  // workspace carve-up (256B aligned)
  auto align_up = [](size_t v) { return (v + 255) & ~(size_t)255; };
  char* p = (char*)d_ws;
  float* Z      = (float*)p;  p += align_up((size_t)N * OH * 4);
  float* el     = (float*)p;  p += align_up((size_t)N * NH * 4);
  float* er     = (float*)p;  p += align_up((size_t)N * NH * 4);
  int*   deg    = (int*)p;    p += align_up((size_t)N * 4);
  int*   off    = (int*)p;    p += align_up((size_t)(N + 1) * 4);
  int*   cursor = (int*)p;    p += align_up((size_t)N * 4);
  int*   sums   = (int*)p;    p += align_up((size_t)64 * 4);
  int*   boff   = (int*)p;    p += align_up((size_t)64 * 4);
  int*   colS   = (int*)p;    p += align_up((size_t)E * 4);
  (void)ws_size; (void)n_in; (void)out_size;

  const int nb = (N + SCAN_B - 1) / SCAN_B;

  // GEMM  Z = X @ W^T + b
  dim3 ggrid(OH / BN, (N + BM - 1) / BM);
  hipLaunchKernelGGL(k_gemm, ggrid, dim3(256), 0, stream, X, W, bias, Z, N);

  // attention logit halves
  hipLaunchKernelGGL(k_elr, dim3((N + 3) / 4), dim3(256), 0, stream,
                     Z, a_l, a_r, el, er, N);

  // CSR build
  hipLaunchKernelGGL(k_zero, dim3((N + 255) / 256), dim3(256), 0, stream, deg, N);
  hipLaunchKernelGGL(k_hist, dim3((E + 255) / 256), dim3(256), 0, stream, row, deg, E);
  hipLaunchKernelGGL(k_scan1, dim3(nb), dim3(SCAN_B), 0, stream, deg, off, sums, N);
  hipLaunchKernelGGL(k_scan2, dim3(1), dim3(64), 0, stream, sums, boff, off, nb, N, E);
  hipLaunchKernelGGL(k_scan3, dim3(nb), dim3(SCAN_B), 0, stream, off, cursor, boff, N);
  hipLaunchKernelGGL(k_fill, dim3((E + 255) / 256), dim3(256), 0, stream,
                     row, col, cursor, colS, E);

  // softmax + weighted aggregation
  hipLaunchKernelGGL(k_agg, dim3((N + 3) / 4), dim3(256), 0, stream,
                     Z, el, er, off, colS, out, N);
}

// Round 2
// 524.843 us; speedup vs baseline: 1.5129x; 1.5129x over previous
//
#include <hip/hip_runtime.h>
#include <hip/hip_fp16.h>

#define IN_F 512
#define OH   512   // OUT*H
#define NH   8     // heads

typedef _Float16 half_t;
typedef __attribute__((ext_vector_type(8))) _Float16 f16x8;
typedef __attribute__((ext_vector_type(4))) float    f32x4;

#define GLOBAL_AS const __attribute__((address_space(1))) void
#define LDS_AS    __attribute__((address_space(3))) void

__device__ static inline void gload_lds16(const void* g, void* l) {
  __builtin_amdgcn_global_load_lds((GLOBAL_AS*)g, (LDS_AS*)l, 16, 0, 0);
}

// ---------------------------------------------------------------------------
// cast f32 -> f16 for X and W (one grid, 8 elems/thread)
// ---------------------------------------------------------------------------
__global__ __launch_bounds__(256) void k_cast(const float* __restrict__ X,
                                              half_t* __restrict__ Xh, size_t nX,
                                              const float* __restrict__ W,
                                              half_t* __restrict__ Wh, size_t nW) {
  size_t i = ((size_t)blockIdx.x * blockDim.x + threadIdx.x) * 8;
  size_t nTot = nX + nW;
  if (i >= nTot) return;
  const float* src; half_t* dst; size_t o;
  if (i < nX) { src = X; dst = Xh; o = i; }
  else        { src = W; dst = Wh; o = i - nX; }
  float4 a = *(const float4*)(src + o);
  float4 b = *(const float4*)(src + o + 4);
  f16x8 h;
  h[0] = (half_t)a.x; h[1] = (half_t)a.y; h[2] = (half_t)a.z; h[3] = (half_t)a.w;
  h[4] = (half_t)b.x; h[5] = (half_t)b.y; h[6] = (half_t)b.z; h[7] = (half_t)b.w;
  *(f16x8*)(dst + o) = h;
}

// ---------------------------------------------------------------------------
// MFMA f16 GEMM: Zh[n, j] = (half) (sum_k Xh[n,k]*Wh[j,k] + bias[j])
// 128x128 tile, BK=32, 4 waves (2x2), m97 structure with global_load_lds.
// ---------------------------------------------------------------------------
__global__ __launch_bounds__(256) void k_gemm16(const half_t* __restrict__ Xh,
                                                const half_t* __restrict__ Wh,
                                                const float* __restrict__ bias,
                                                half_t* __restrict__ Zh, int N) {
  __shared__ half_t smem[2][128][32];   // [0]=A tile, [1]=B tile; contiguous 16KB
  const int tid  = threadIdx.x;
  const int lane = tid & 63;
  const int wid  = tid >> 6;
  const int wr = wid >> 1, wc = wid & 1;
  const int n0 = blockIdx.y * 128;
  const int j0 = blockIdx.x * 128;

  f32x4 acc[4][4] = {};

  char* smem_base = (char*)&smem[0][0][0];
  const int rl = lane & 15;
  const int kg = (lane >> 4) * 8;   // k-offset within BK: 0,8,16,24

  for (int kt = 0; kt < IN_F; kt += 32) {
    // ---- stage 16KB: wave wid owns LDS bytes [wid*4K, wid*4K+4K), 4 calls x 1KB
#pragma unroll
    for (int c = 0; c < 4; c++) {
      int o = wid * 4096 + c * 1024 + lane * 16;   // linear LDS byte
      int rrow = o >> 6;          // 0..255 (0..127 = A rows, 128..255 = B rows)
      int colh = (o & 63) >> 1;   // half-element offset within 32-wide row
      const half_t* g;
      if (rrow < 128) {
        int n = n0 + rrow; if (n > N - 1) n = N - 1;
        g = Xh + (size_t)n * IN_F + kt + colh;
      } else {
        g = Wh + (size_t)(j0 + (rrow - 128)) * IN_F + kt + colh;
      }
      char* l = smem_base + wid * 4096 + c * 1024;  // wave-uniform base
      gload_lds16(g, l);
    }
    __syncthreads();   // drains vmcnt -> tiles visible

    f16x8 af[4], bf[4];
#pragma unroll
    for (int m = 0; m < 4; m++)
      af[m] = *(const f16x8*)&smem[0][wr * 64 + m * 16 + rl][kg];
#pragma unroll
    for (int n = 0; n < 4; n++)
      bf[n] = *(const f16x8*)&smem[1][wc * 64 + n * 16 + rl][kg];

#pragma unroll
    for (int m = 0; m < 4; m++)
#pragma unroll
      for (int n = 0; n < 4; n++)
        acc[m][n] = __builtin_amdgcn_mfma_f32_16x16x32_f16(af[m], bf[n], acc[m][n], 0, 0, 0);
    __syncthreads();   // protect LDS before next stage
  }

  // ---- epilogue: C/D layout col=lane&15, row=(lane>>4)*4+q
#pragma unroll
  for (int n = 0; n < 4; n++) {
    int j = j0 + wc * 64 + n * 16 + rl;
    float bv = bias[j];
#pragma unroll
    for (int m = 0; m < 4; m++) {
      int rbase = n0 + wr * 64 + m * 16 + (lane >> 4) * 4;
#pragma unroll
      for (int q = 0; q < 4; q++) {
        int nrow = rbase + q;
        if (nrow < N) Zh[(size_t)nrow * OH + j] = (half_t)(acc[m][n][q] + bv);
      }
    }
  }
}

// ---------------------------------------------------------------------------
// e_l[n,h] = sum_o Z[n,o,h]*a_l[o,h];  e_r likewise. One wave per node.
// ---------------------------------------------------------------------------
__global__ __launch_bounds__(256) void k_elr(const half_t* __restrict__ Zh,
                                             const float* __restrict__ al,
                                             const float* __restrict__ ar,
                                             float* __restrict__ el,
                                             float* __restrict__ er, int N) {
  int wid = threadIdx.x >> 6, lane = threadIdx.x & 63;
  int n = blockIdx.x * 4 + wid;
  if (n >= N) return;
  f16x8 z = *(const f16x8*)(Zh + (size_t)n * OH + lane * 8);
  const float4* ap = (const float4*)(al + lane * 8);
  float4 a0 = ap[0], a1 = ap[1];
  const float4* bp = (const float4*)(ar + lane * 8);
  float4 b0 = bp[0], b1 = bp[1];
  float zf[8];
#pragma unroll
  for (int j = 0; j < 8; j++) zf[j] = (float)z[j];

  float pl[8] = {zf[0] * a0.x, zf[1] * a0.y, zf[2] * a0.z, zf[3] * a0.w,
                 zf[4] * a1.x, zf[5] * a1.y, zf[6] * a1.z, zf[7] * a1.w};
  float pr[8] = {zf[0] * b0.x, zf[1] * b0.y, zf[2] * b0.z, zf[3] * b0.w,
                 zf[4] * b1.x, zf[5] * b1.y, zf[6] * b1.z, zf[7] * b1.w};
#pragma unroll
  for (int s = 1; s < 64; s <<= 1) {
#pragma unroll
    for (int h = 0; h < 8; h++) {
      pl[h] += __shfl_xor(pl[h], s);
      pr[h] += __shfl_xor(pr[h], s);
    }
  }
  if (lane == 0) {
    float4* e0 = (float4*)(el + (size_t)n * NH);
    e0[0] = make_float4(pl[0], pl[1], pl[2], pl[3]);
    e0[1] = make_float4(pl[4], pl[5], pl[6], pl[7]);
    float4* e1 = (float4*)(er + (size_t)n * NH);
    e1[0] = make_float4(pr[0], pr[1], pr[2], pr[3]);
    e1[1] = make_float4(pr[4], pr[5], pr[6], pr[7]);
  }
}

// ---------------------------------------------------------------------------
// CSR build
// ---------------------------------------------------------------------------
__global__ void k_zero(int* __restrict__ p, int n) {
  int i = blockIdx.x * blockDim.x + threadIdx.x;
  if (i < n) p[i] = 0;
}

__global__ void k_hist(const int* __restrict__ row, int* __restrict__ deg, int E) {
  int e = blockIdx.x * blockDim.x + threadIdx.x;
  if (e < E) atomicAdd(&deg[row[e]], 1);
}

#define SCAN_B 1024
__global__ __launch_bounds__(SCAN_B) void k_scan1(const int* __restrict__ deg,
                                                  int* __restrict__ off,
                                                  int* __restrict__ sums, int N) {
  __shared__ int s[SCAN_B];
  int tid = threadIdx.x;
  int g = blockIdx.x * SCAN_B + tid;
  int v = (g < N) ? deg[g] : 0;
  s[tid] = v;
  __syncthreads();
  for (int o = 1; o < SCAN_B; o <<= 1) {
    int t = (tid >= o) ? s[tid - o] : 0;
    __syncthreads();
    s[tid] += t;
    __syncthreads();
  }
  if (g < N) off[g] = s[tid] - v;
  if (tid == SCAN_B - 1) sums[blockIdx.x] = s[tid];
}

__global__ void k_scan2(const int* __restrict__ sums, int* __restrict__ boff,
                        int* __restrict__ off, int nb, int N, int E) {
  if (threadIdx.x == 0 && blockIdx.x == 0) {
    int run = 0;
    for (int b = 0; b < nb; ++b) { boff[b] = run; run += sums[b]; }
    off[N] = E;
  }
}

__global__ __launch_bounds__(SCAN_B) void k_scan3(int* __restrict__ off,
                                                  int* __restrict__ cursor,
                                                  const int* __restrict__ boff, int N) {
  int g = blockIdx.x * SCAN_B + threadIdx.x;
  if (g < N) {
    int v = off[g] + boff[blockIdx.x];
    off[g] = v;
    cursor[g] = v;
  }
}

__global__ void k_fill(const int* __restrict__ row, const int* __restrict__ col,
                       int* __restrict__ cursor, int* __restrict__ colS, int E) {
  int e = blockIdx.x * blockDim.x + threadIdx.x;
  if (e < E) {
    int r = row[e];
    int p = atomicAdd(&cursor[r], 1);
    colS[p] = col[e];
  }
}

// ---------------------------------------------------------------------------
// Aggregation: one wave per destination row i. Zh is f16 (1KB/row gathers).
// ---------------------------------------------------------------------------
__global__ __launch_bounds__(256) void k_agg(const half_t* __restrict__ Zh,
                                             const float* __restrict__ el,
                                             const float* __restrict__ er,
                                             const int* __restrict__ off,
                                             const int* __restrict__ colS,
                                             float* __restrict__ out, int N) {
  int wid = threadIdx.x >> 6, lane = threadIdx.x & 63;
  int i = blockIdx.x * 4 + wid;
  if (i >= N) return;
  int s = off[i], t = off[i + 1];

  float eli[8];
  {
    const float4* e4 = (const float4*)(el + (size_t)i * NH);
    float4 a = e4[0], b = e4[1];
    eli[0] = a.x; eli[1] = a.y; eli[2] = a.z; eli[3] = a.w;
    eli[4] = b.x; eli[5] = b.y; eli[6] = b.z; eli[7] = b.w;
  }

  float m[8];
#pragma unroll
  for (int h = 0; h < 8; h++) m[h] = -1e30f;

  for (int p = s; p < t; p++) {
    int c = colS[p];
    const float4* e4 = (const float4*)(er + (size_t)c * NH);
    float4 ea = e4[0], eb = e4[1];
    float ev[8] = {ea.x, ea.y, ea.z, ea.w, eb.x, eb.y, eb.z, eb.w};
#pragma unroll
    for (int h = 0; h < 8; h++) {
      float eh = eli[h] + ev[h];
      eh = (eh > 0.f) ? eh : 0.01f * eh;
      m[h] = fmaxf(m[h], eh);
    }
  }

  float den[8], acc[8];
#pragma unroll
  for (int h = 0; h < 8; h++) { den[h] = 0.f; acc[h] = 0.f; }

  for (int p = s; p < t; p++) {
    int c = colS[p];
    const float4* e4 = (const float4*)(er + (size_t)c * NH);
    float4 ea = e4[0], eb = e4[1];
    float ev[8] = {ea.x, ea.y, ea.z, ea.w, eb.x, eb.y, eb.z, eb.w};
    float pr[8];
#pragma unroll
    for (int h = 0; h < 8; h++) {
      float eh = eli[h] + ev[h];
      eh = (eh > 0.f) ? eh : 0.01f * eh;
      pr[h] = __expf(eh - m[h]);
      den[h] += pr[h];
    }
    f16x8 z = *(const f16x8*)(Zh + (size_t)c * OH + lane * 8);
#pragma unroll
    for (int h = 0; h < 8; h++) acc[h] = fmaf(pr[h], (float)z[h], acc[h]);
  }

  float4 o0, o1;
  if (t > s) {
    o0 = make_float4(acc[0] / den[0], acc[1] / den[1], acc[2] / den[2], acc[3] / den[3]);
    o1 = make_float4(acc[4] / den[4], acc[5] / den[5], acc[6] / den[6], acc[7] / den[7]);
  } else {
    o0 = make_float4(0.f, 0.f, 0.f, 0.f);
    o1 = o0;
  }
  *(float4*)(out + (size_t)i * OH + lane * 8)     = o0;
  *(float4*)(out + (size_t)i * OH + lane * 8 + 4) = o1;
}

// ---------------------------------------------------------------------------
extern "C" void kernel_launch(void* const* d_in, const int* in_sizes, int n_in,
                              void* d_out, int out_size, void* d_ws, size_t ws_size,
                              hipStream_t stream) {
  const float* X    = (const float*)d_in[0];
  const float* W    = (const float*)d_in[1];
  const float* bias = (const float*)d_in[2];
  const float* a_l  = (const float*)d_in[3];
  const float* a_r  = (const float*)d_in[4];
  const int*   row  = (const int*)d_in[5];
  const int*   col  = (const int*)d_in[6];
  float* out = (float*)d_out;

  const int N = in_sizes[0] / IN_F;   // 50000
  const int E = in_sizes[5];          // 850000
  const size_t nX = (size_t)N * IN_F;
  const size_t nW = (size_t)OH * IN_F;

  auto align_up = [](size_t v) { return (v + 255) & ~(size_t)255; };
  char* p = (char*)d_ws;
  half_t* Xh    = (half_t*)p; p += align_up(nX * 2);
  half_t* Wh    = (half_t*)p; p += align_up(nW * 2);
  half_t* Zh    = (half_t*)p; p += align_up((size_t)N * OH * 2);
  float* el     = (float*)p;  p += align_up((size_t)N * NH * 4);
  float* er     = (float*)p;  p += align_up((size_t)N * NH * 4);
  int*   deg    = (int*)p;    p += align_up((size_t)N * 4);
  int*   off    = (int*)p;    p += align_up((size_t)(N + 1) * 4);
  int*   cursor = (int*)p;    p += align_up((size_t)N * 4);
  int*   sums   = (int*)p;    p += align_up((size_t)64 * 4);
  int*   boff   = (int*)p;    p += align_up((size_t)64 * 4);
  int*   colS   = (int*)p;    p += align_up((size_t)E * 4);
  (void)ws_size; (void)n_in; (void)out_size;

  const int nb = (N + SCAN_B - 1) / SCAN_B;

  // cast X, W to f16
  size_t nTot8 = (nX + nW) / 8;
  hipLaunchKernelGGL(k_cast, dim3((nTot8 + 255) / 256), dim3(256), 0, stream,
                     X, Xh, nX, W, Wh, nW);

  // MFMA GEMM  Zh = f16(X @ W^T + b)
  dim3 ggrid(OH / 128, (N + 127) / 128);
  hipLaunchKernelGGL(k_gemm16, ggrid, dim3(256), 0, stream, Xh, Wh, bias, Zh, N);

  // attention logit halves
  hipLaunchKernelGGL(k_elr, dim3((N + 3) / 4), dim3(256), 0, stream,
                     Zh, a_l, a_r, el, er, N);

  // CSR build
  hipLaunchKernelGGL(k_zero, dim3((N + 255) / 256), dim3(256), 0, stream, deg, N);
  hipLaunchKernelGGL(k_hist, dim3((E + 255) / 256), dim3(256), 0, stream, row, deg, E);
  hipLaunchKernelGGL(k_scan1, dim3(nb), dim3(SCAN_B), 0, stream, deg, off, sums, N);
  hipLaunchKernelGGL(k_scan2, dim3(1), dim3(64), 0, stream, sums, boff, off, nb, N, E);
  hipLaunchKernelGGL(k_scan3, dim3(nb), dim3(SCAN_B), 0, stream, off, cursor, boff, N);
  hipLaunchKernelGGL(k_fill, dim3((E + 255) / 256), dim3(256), 0, stream,
                     row, col, cursor, colS, E);

  // softmax + weighted aggregation
  hipLaunchKernelGGL(k_agg, dim3((N + 3) / 4), dim3(256), 0, stream,
                     Zh, el, er, off, colS, out, N);
}

// Round 3
// 427.098 us; speedup vs baseline: 1.8591x; 1.2289x over previous
//
#include <hip/hip_runtime.h>
#include <hip/hip_fp16.h>

#define IN_F 512
#define OH   512   // OUT*H
#define NH   8     // heads

typedef _Float16 half_t;
typedef __attribute__((ext_vector_type(8))) _Float16 f16x8;
typedef __attribute__((ext_vector_type(4))) float    f32x4;

#define GLOBAL_AS const __attribute__((address_space(1))) void
#define LDS_AS    __attribute__((address_space(3))) void

__device__ static inline void gload_lds16(const void* g, void* l) {
  __builtin_amdgcn_global_load_lds((GLOBAL_AS*)g, (LDS_AS*)l, 16, 0, 0);
}

// ---------------------------------------------------------------------------
// cast f32 -> f16 for X and W (one grid, 8 elems/thread)
// ---------------------------------------------------------------------------
__global__ __launch_bounds__(256) void k_cast(const float* __restrict__ X,
                                              half_t* __restrict__ Xh, size_t nX,
                                              const float* __restrict__ W,
                                              half_t* __restrict__ Wh, size_t nW) {
  size_t i = ((size_t)blockIdx.x * blockDim.x + threadIdx.x) * 8;
  size_t nTot = nX + nW;
  if (i >= nTot) return;
  const float* src; half_t* dst; size_t o;
  if (i < nX) { src = X; dst = Xh; o = i; }
  else        { src = W; dst = Wh; o = i - nX; }
  float4 a = *(const float4*)(src + o);
  float4 b = *(const float4*)(src + o + 4);
  f16x8 h;
  h[0] = (half_t)a.x; h[1] = (half_t)a.y; h[2] = (half_t)a.z; h[3] = (half_t)a.w;
  h[4] = (half_t)b.x; h[5] = (half_t)b.y; h[6] = (half_t)b.z; h[7] = (half_t)b.w;
  *(f16x8*)(dst + o) = h;
}

// ---------------------------------------------------------------------------
// MFMA f16 GEMM: Zh[n, j] = (half) (sum_k Xh[n,k]*Wh[j,k] + bias[j])
// 128x128 tile, BK=32, 4 waves (2x2), m97 structure with global_load_lds.
// ---------------------------------------------------------------------------
__global__ __launch_bounds__(256) void k_gemm16(const half_t* __restrict__ Xh,
                                                const half_t* __restrict__ Wh,
                                                const float* __restrict__ bias,
                                                half_t* __restrict__ Zh, int N) {
  __shared__ half_t smem[2][128][32];   // [0]=A tile, [1]=B tile; contiguous 16KB
  const int tid  = threadIdx.x;
  const int lane = tid & 63;
  const int wid  = tid >> 6;
  const int wr = wid >> 1, wc = wid & 1;
  const int n0 = blockIdx.y * 128;
  const int j0 = blockIdx.x * 128;

  f32x4 acc[4][4] = {};

  char* smem_base = (char*)&smem[0][0][0];
  const int rl = lane & 15;
  const int kg = (lane >> 4) * 8;   // k-offset within BK: 0,8,16,24

  for (int kt = 0; kt < IN_F; kt += 32) {
#pragma unroll
    for (int c = 0; c < 4; c++) {
      int o = wid * 4096 + c * 1024 + lane * 16;   // linear LDS byte
      int rrow = o >> 6;          // 0..255 (0..127 = A rows, 128..255 = B rows)
      int colh = (o & 63) >> 1;   // half-element offset within 32-wide row
      const half_t* g;
      if (rrow < 128) {
        int n = n0 + rrow; if (n > N - 1) n = N - 1;
        g = Xh + (size_t)n * IN_F + kt + colh;
      } else {
        g = Wh + (size_t)(j0 + (rrow - 128)) * IN_F + kt + colh;
      }
      char* l = smem_base + wid * 4096 + c * 1024;  // wave-uniform base
      gload_lds16(g, l);
    }
    __syncthreads();

    f16x8 af[4], bf[4];
#pragma unroll
    for (int m = 0; m < 4; m++)
      af[m] = *(const f16x8*)&smem[0][wr * 64 + m * 16 + rl][kg];
#pragma unroll
    for (int n = 0; n < 4; n++)
      bf[n] = *(const f16x8*)&smem[1][wc * 64 + n * 16 + rl][kg];

#pragma unroll
    for (int m = 0; m < 4; m++)
#pragma unroll
      for (int n = 0; n < 4; n++)
        acc[m][n] = __builtin_amdgcn_mfma_f32_16x16x32_f16(af[m], bf[n], acc[m][n], 0, 0, 0);
    __syncthreads();
  }

#pragma unroll
  for (int n = 0; n < 4; n++) {
    int j = j0 + wc * 64 + n * 16 + rl;
    float bv = bias[j];
#pragma unroll
    for (int m = 0; m < 4; m++) {
      int rbase = n0 + wr * 64 + m * 16 + (lane >> 4) * 4;
#pragma unroll
      for (int q = 0; q < 4; q++) {
        int nrow = rbase + q;
        if (nrow < N) Zh[(size_t)nrow * OH + j] = (half_t)(acc[m][n][q] + bv);
      }
    }
  }
}

// ---------------------------------------------------------------------------
// e_l[n,h] = sum_o Z[n,o,h]*a_l[o,h];  e_r likewise. One wave per node.
// ---------------------------------------------------------------------------
__global__ __launch_bounds__(256) void k_elr(const half_t* __restrict__ Zh,
                                             const float* __restrict__ al,
                                             const float* __restrict__ ar,
                                             float* __restrict__ el,
                                             float* __restrict__ er, int N) {
  int wid = threadIdx.x >> 6, lane = threadIdx.x & 63;
  int n = blockIdx.x * 4 + wid;
  if (n >= N) return;
  f16x8 z = *(const f16x8*)(Zh + (size_t)n * OH + lane * 8);
  const float4* ap = (const float4*)(al + lane * 8);
  float4 a0 = ap[0], a1 = ap[1];
  const float4* bp = (const float4*)(ar + lane * 8);
  float4 b0 = bp[0], b1 = bp[1];
  float zf[8];
#pragma unroll
  for (int j = 0; j < 8; j++) zf[j] = (float)z[j];

  float pl[8] = {zf[0] * a0.x, zf[1] * a0.y, zf[2] * a0.z, zf[3] * a0.w,
                 zf[4] * a1.x, zf[5] * a1.y, zf[6] * a1.z, zf[7] * a1.w};
  float pr[8] = {zf[0] * b0.x, zf[1] * b0.y, zf[2] * b0.z, zf[3] * b0.w,
                 zf[4] * b1.x, zf[5] * b1.y, zf[6] * b1.z, zf[7] * b1.w};
#pragma unroll
  for (int s = 1; s < 64; s <<= 1) {
#pragma unroll
    for (int h = 0; h < 8; h++) {
      pl[h] += __shfl_xor(pl[h], s);
      pr[h] += __shfl_xor(pr[h], s);
    }
  }
  if (lane == 0) {
    float4* e0 = (float4*)(el + (size_t)n * NH);
    e0[0] = make_float4(pl[0], pl[1], pl[2], pl[3]);
    e0[1] = make_float4(pl[4], pl[5], pl[6], pl[7]);
    float4* e1 = (float4*)(er + (size_t)n * NH);
    e1[0] = make_float4(pr[0], pr[1], pr[2], pr[3]);
    e1[1] = make_float4(pr[4], pr[5], pr[6], pr[7]);
  }
}

// ---------------------------------------------------------------------------
// CSR build
// ---------------------------------------------------------------------------
__global__ void k_zero(int* __restrict__ p, int n) {
  int i = blockIdx.x * blockDim.x + threadIdx.x;
  if (i < n) p[i] = 0;
}

__global__ void k_hist(const int* __restrict__ row, int* __restrict__ deg, int E) {
  int e = blockIdx.x * blockDim.x + threadIdx.x;
  if (e < E) atomicAdd(&deg[row[e]], 1);
}

#define SCAN_B 1024
__global__ __launch_bounds__(SCAN_B) void k_scan1(const int* __restrict__ deg,
                                                  int* __restrict__ off,
                                                  int* __restrict__ sums, int N) {
  __shared__ int s[SCAN_B];
  int tid = threadIdx.x;
  int g = blockIdx.x * SCAN_B + tid;
  int v = (g < N) ? deg[g] : 0;
  s[tid] = v;
  __syncthreads();
  for (int o = 1; o < SCAN_B; o <<= 1) {
    int t = (tid >= o) ? s[tid - o] : 0;
    __syncthreads();
    s[tid] += t;
    __syncthreads();
  }
  if (g < N) off[g] = s[tid] - v;
  if (tid == SCAN_B - 1) sums[blockIdx.x] = s[tid];
}

__global__ void k_scan2(const int* __restrict__ sums, int* __restrict__ boff,
                        int* __restrict__ off, int nb, int N, int E) {
  if (threadIdx.x == 0 && blockIdx.x == 0) {
    int run = 0;
    for (int b = 0; b < nb; ++b) { boff[b] = run; run += sums[b]; }
    off[N] = E;
  }
}

__global__ __launch_bounds__(SCAN_B) void k_scan3(int* __restrict__ off,
                                                  int* __restrict__ cursor,
                                                  const int* __restrict__ boff, int N) {
  int g = blockIdx.x * SCAN_B + threadIdx.x;
  if (g < N) {
    int v = off[g] + boff[blockIdx.x];
    off[g] = v;
    cursor[g] = v;
  }
}

__global__ void k_fill(const int* __restrict__ row, const int* __restrict__ col,
                       int* __restrict__ cursor, int* __restrict__ colS, int E) {
  int e = blockIdx.x * blockDim.x + threadIdx.x;
  if (e < E) {
    int r = row[e];
    int p = atomicAdd(&cursor[r], 1);
    colS[p] = col[e];
  }
}

// ---------------------------------------------------------------------------
// Edge softmax numerators + denominators.  One wave per node, lanes parallel
// over the node's edges.  exS[p][h] = exp(e - m);  den[i][h] = sum.
// ---------------------------------------------------------------------------
__global__ __launch_bounds__(256) void k_edgew(const float* __restrict__ el,
                                               const float* __restrict__ er,
                                               const int* __restrict__ off,
                                               const int* __restrict__ colS,
                                               float* __restrict__ exS,
                                               float* __restrict__ den, int N) {
  int wid = threadIdx.x >> 6, lane = threadIdx.x & 63;
  int i = blockIdx.x * 4 + wid;
  if (i >= N) return;
  int s = off[i], t = off[i + 1];

  float eli[8];
  {
    const float4* e4 = (const float4*)(el + (size_t)i * NH);
    float4 a = e4[0], b = e4[1];
    eli[0] = a.x; eli[1] = a.y; eli[2] = a.z; eli[3] = a.w;
    eli[4] = b.x; eli[5] = b.y; eli[6] = b.z; eli[7] = b.w;
  }

  float m[8];
#pragma unroll
  for (int h = 0; h < 8; h++) m[h] = -1e30f;

  for (int p = s + lane; p < t; p += 64) {
    int c = colS[p];
    const float4* e4 = (const float4*)(er + (size_t)c * NH);
    float4 ea = e4[0], eb = e4[1];
    float ev[8] = {ea.x, ea.y, ea.z, ea.w, eb.x, eb.y, eb.z, eb.w};
#pragma unroll
    for (int h = 0; h < 8; h++) {
      float eh = eli[h] + ev[h];
      eh = (eh > 0.f) ? eh : 0.01f * eh;
      m[h] = fmaxf(m[h], eh);
    }
  }
#pragma unroll
  for (int st = 1; st < 64; st <<= 1)
#pragma unroll
    for (int h = 0; h < 8; h++) m[h] = fmaxf(m[h], __shfl_xor(m[h], st));

  float d[8];
#pragma unroll
  for (int h = 0; h < 8; h++) d[h] = 0.f;

  for (int p = s + lane; p < t; p += 64) {
    int c = colS[p];
    const float4* e4 = (const float4*)(er + (size_t)c * NH);
    float4 ea = e4[0], eb = e4[1];
    float ev[8] = {ea.x, ea.y, ea.z, ea.w, eb.x, eb.y, eb.z, eb.w};
    float pr[8];
#pragma unroll
    for (int h = 0; h < 8; h++) {
      float eh = eli[h] + ev[h];
      eh = (eh > 0.f) ? eh : 0.01f * eh;
      pr[h] = __expf(eh - m[h]);
      d[h] += pr[h];
    }
    float4* o4 = (float4*)(exS + (size_t)p * NH);
    o4[0] = make_float4(pr[0], pr[1], pr[2], pr[3]);
    o4[1] = make_float4(pr[4], pr[5], pr[6], pr[7]);
  }
#pragma unroll
  for (int st = 1; st < 64; st <<= 1)
#pragma unroll
    for (int h = 0; h < 8; h++) d[h] += __shfl_xor(d[h], st);

  if (lane == 0) {
    float4* d4 = (float4*)(den + (size_t)i * NH);
    d4[0] = make_float4(d[0], d[1], d[2], d[3]);
    d4[1] = make_float4(d[4], d[5], d[6], d[7]);
  }
}

// ---------------------------------------------------------------------------
// Aggregation: one wave per destination row i; weights precomputed.
// ---------------------------------------------------------------------------
__global__ __launch_bounds__(256) void k_agg2(const half_t* __restrict__ Zh,
                                              const float* __restrict__ exS,
                                              const float* __restrict__ den,
                                              const int* __restrict__ off,
                                              const int* __restrict__ colS,
                                              float* __restrict__ out, int N) {
  int wid = threadIdx.x >> 6, lane = threadIdx.x & 63;
  int i = blockIdx.x * 4 + wid;
  if (i >= N) return;
  int s = off[i], t = off[i + 1];

  float inv[8];
  {
    const float4* d4 = (const float4*)(den + (size_t)i * NH);
    float4 a = d4[0], b = d4[1];
    inv[0] = 1.f / a.x; inv[1] = 1.f / a.y; inv[2] = 1.f / a.z; inv[3] = 1.f / a.w;
    inv[4] = 1.f / b.x; inv[5] = 1.f / b.y; inv[6] = 1.f / b.z; inv[7] = 1.f / b.w;
  }

  float acc[8];
#pragma unroll
  for (int h = 0; h < 8; h++) acc[h] = 0.f;

  int c = (t > s) ? colS[s] : 0;
  for (int p = s; p < t; p++) {
    int cn = (p + 1 < t) ? colS[p + 1] : 0;   // lookahead: hide index latency
    const float4* a4 = (const float4*)(exS + (size_t)p * NH);
    float4 a0 = a4[0], a1 = a4[1];
    float av[8] = {a0.x, a0.y, a0.z, a0.w, a1.x, a1.y, a1.z, a1.w};
    f16x8 z = *(const f16x8*)(Zh + (size_t)c * OH + lane * 8);
#pragma unroll
    for (int h = 0; h < 8; h++) acc[h] = fmaf(av[h], (float)z[h], acc[h]);
    c = cn;
  }

  float4 o0 = make_float4(acc[0] * inv[0], acc[1] * inv[1], acc[2] * inv[2], acc[3] * inv[3]);
  float4 o1 = make_float4(acc[4] * inv[4], acc[5] * inv[5], acc[6] * inv[6], acc[7] * inv[7]);
  *(float4*)(out + (size_t)i * OH + lane * 8)     = o0;
  *(float4*)(out + (size_t)i * OH + lane * 8 + 4) = o1;
}

// ---------------------------------------------------------------------------
extern "C" void kernel_launch(void* const* d_in, const int* in_sizes, int n_in,
                              void* d_out, int out_size, void* d_ws, size_t ws_size,
                              hipStream_t stream) {
  const float* X    = (const float*)d_in[0];
  const float* W    = (const float*)d_in[1];
  const float* bias = (const float*)d_in[2];
  const float* a_l  = (const float*)d_in[3];
  const float* a_r  = (const float*)d_in[4];
  const int*   row  = (const int*)d_in[5];
  const int*   col  = (const int*)d_in[6];
  float* out = (float*)d_out;

  const int N = in_sizes[0] / IN_F;   // 50000
  const int E = in_sizes[5];          // 850000
  const size_t nX = (size_t)N * IN_F;
  const size_t nW = (size_t)OH * IN_F;

  auto align_up = [](size_t v) { return (v + 255) & ~(size_t)255; };
  char* p = (char*)d_ws;
  half_t* Xh    = (half_t*)p; p += align_up(nX * 2);      // dead after GEMM
  half_t* Wh    = (half_t*)p; p += align_up(nW * 2);
  half_t* Zh    = (half_t*)p; p += align_up((size_t)N * OH * 2);
  float* el     = (float*)p;  p += align_up((size_t)N * NH * 4);
  float* er     = (float*)p;  p += align_up((size_t)N * NH * 4);
  float* den    = (float*)p;  p += align_up((size_t)N * NH * 4);
  int*   deg    = (int*)p;    p += align_up((size_t)N * 4);
  int*   off    = (int*)p;    p += align_up((size_t)(N + 1) * 4);
  int*   cursor = (int*)p;    p += align_up((size_t)N * 4);
  int*   sums   = (int*)p;    p += align_up((size_t)64 * 4);
  int*   boff   = (int*)p;    p += align_up((size_t)64 * 4);
  int*   colS   = (int*)p;    p += align_up((size_t)E * 4);
  float* exS    = (float*)Xh;   // alias: Xh (51 MB) >= exS (E*8*4 = 27 MB)
  (void)ws_size; (void)n_in; (void)out_size;

  const int nb = (N + SCAN_B - 1) / SCAN_B;

  // cast X, W to f16
  size_t nTot8 = (nX + nW) / 8;
  hipLaunchKernelGGL(k_cast, dim3((nTot8 + 255) / 256), dim3(256), 0, stream,
                     X, Xh, nX, W, Wh, nW);

  // MFMA GEMM  Zh = f16(X @ W^T + b)
  dim3 ggrid(OH / 128, (N + 127) / 128);
  hipLaunchKernelGGL(k_gemm16, ggrid, dim3(256), 0, stream, Xh, Wh, bias, Zh, N);

  // attention logit halves
  hipLaunchKernelGGL(k_elr, dim3((N + 3) / 4), dim3(256), 0, stream,
                     Zh, a_l, a_r, el, er, N);

  // CSR build
  hipLaunchKernelGGL(k_zero, dim3((N + 255) / 256), dim3(256), 0, stream, deg, N);
  hipLaunchKernelGGL(k_hist, dim3((E + 255) / 256), dim3(256), 0, stream, row, deg, E);
  hipLaunchKernelGGL(k_scan1, dim3(nb), dim3(SCAN_B), 0, stream, deg, off, sums, N);
  hipLaunchKernelGGL(k_scan2, dim3(1), dim3(64), 0, stream, sums, boff, off, nb, N, E);
  hipLaunchKernelGGL(k_scan3, dim3(nb), dim3(SCAN_B), 0, stream, off, cursor, boff, N);
  hipLaunchKernelGGL(k_fill, dim3((E + 255) / 256), dim3(256), 0, stream,
                     row, col, cursor, colS, E);

  // edge softmax weights (exS aliases Xh -- GEMM is done by now)
  hipLaunchKernelGGL(k_edgew, dim3((N + 3) / 4), dim3(256), 0, stream,
                     el, er, off, colS, exS, den, N);

  // weighted aggregation
  hipLaunchKernelGGL(k_agg2, dim3((N + 3) / 4), dim3(256), 0, stream,
                     Zh, exS, den, off, colS, out, N);
}

// Round 4
// 386.075 us; speedup vs baseline: 2.0567x; 1.1063x over previous
//
#include <hip/hip_runtime.h>
#include <hip/hip_fp16.h>

#define IN_F 512
#define OH   512   // OUT*H
#define NH   8     // heads

typedef _Float16 half_t;
typedef __attribute__((ext_vector_type(8))) _Float16 f16x8;
typedef __attribute__((ext_vector_type(4))) float    f32x4;

#define GLOBAL_AS const __attribute__((address_space(1))) void
#define LDS_AS    __attribute__((address_space(3))) void

__device__ static inline void gload_lds16(const void* g, void* l) {
  __builtin_amdgcn_global_load_lds((GLOBAL_AS*)g, (LDS_AS*)l, 16, 0, 0);
}

// ---------------------------------------------------------------------------
// cast f32 -> f16 for X and W (one grid, 8 elems/thread)
// ---------------------------------------------------------------------------
__global__ __launch_bounds__(256) void k_cast(const float* __restrict__ X,
                                              half_t* __restrict__ Xh, size_t nX,
                                              const float* __restrict__ W,
                                              half_t* __restrict__ Wh, size_t nW) {
  size_t i = ((size_t)blockIdx.x * blockDim.x + threadIdx.x) * 8;
  size_t nTot = nX + nW;
  if (i >= nTot) return;
  const float* src; half_t* dst; size_t o;
  if (i < nX) { src = X; dst = Xh; o = i; }
  else        { src = W; dst = Wh; o = i - nX; }
  float4 a = *(const float4*)(src + o);
  float4 b = *(const float4*)(src + o + 4);
  f16x8 h;
  h[0] = (half_t)a.x; h[1] = (half_t)a.y; h[2] = (half_t)a.z; h[3] = (half_t)a.w;
  h[4] = (half_t)b.x; h[5] = (half_t)b.y; h[6] = (half_t)b.z; h[7] = (half_t)b.w;
  *(f16x8*)(dst + o) = h;
}

// ---------------------------------------------------------------------------
// MFMA f16 GEMM: Zh[n, j] = (half) (sum_k Xh[n,k]*Wh[j,k] + bias[j])
// 128x128 tile, BK=32, 4 waves (2x2), m97 structure with global_load_lds.
// ---------------------------------------------------------------------------
__global__ __launch_bounds__(256) void k_gemm16(const half_t* __restrict__ Xh,
                                                const half_t* __restrict__ Wh,
                                                const float* __restrict__ bias,
                                                half_t* __restrict__ Zh, int N) {
  __shared__ half_t smem[2][128][32];   // [0]=A tile, [1]=B tile; contiguous 16KB
  const int tid  = threadIdx.x;
  const int lane = tid & 63;
  const int wid  = tid >> 6;
  const int wr = wid >> 1, wc = wid & 1;
  const int n0 = blockIdx.y * 128;
  const int j0 = blockIdx.x * 128;

  f32x4 acc[4][4] = {};

  char* smem_base = (char*)&smem[0][0][0];
  const int rl = lane & 15;
  const int kg = (lane >> 4) * 8;   // k-offset within BK: 0,8,16,24

  for (int kt = 0; kt < IN_F; kt += 32) {
#pragma unroll
    for (int c = 0; c < 4; c++) {
      int o = wid * 4096 + c * 1024 + lane * 16;   // linear LDS byte
      int rrow = o >> 6;          // 0..255 (0..127 = A rows, 128..255 = B rows)
      int colh = (o & 63) >> 1;   // half-element offset within 32-wide row
      const half_t* g;
      if (rrow < 128) {
        int n = n0 + rrow; if (n > N - 1) n = N - 1;
        g = Xh + (size_t)n * IN_F + kt + colh;
      } else {
        g = Wh + (size_t)(j0 + (rrow - 128)) * IN_F + kt + colh;
      }
      char* l = smem_base + wid * 4096 + c * 1024;  // wave-uniform base
      gload_lds16(g, l);
    }
    __syncthreads();

    f16x8 af[4], bf[4];
#pragma unroll
    for (int m = 0; m < 4; m++)
      af[m] = *(const f16x8*)&smem[0][wr * 64 + m * 16 + rl][kg];
#pragma unroll
    for (int n = 0; n < 4; n++)
      bf[n] = *(const f16x8*)&smem[1][wc * 64 + n * 16 + rl][kg];

#pragma unroll
    for (int m = 0; m < 4; m++)
#pragma unroll
      for (int n = 0; n < 4; n++)
        acc[m][n] = __builtin_amdgcn_mfma_f32_16x16x32_f16(af[m], bf[n], acc[m][n], 0, 0, 0);
    __syncthreads();
  }

#pragma unroll
  for (int n = 0; n < 4; n++) {
    int j = j0 + wc * 64 + n * 16 + rl;
    float bv = bias[j];
#pragma unroll
    for (int m = 0; m < 4; m++) {
      int rbase = n0 + wr * 64 + m * 16 + (lane >> 4) * 4;
#pragma unroll
      for (int q = 0; q < 4; q++) {
        int nrow = rbase + q;
        if (nrow < N) Zh[(size_t)nrow * OH + j] = (half_t)(acc[m][n][q] + bv);
      }
    }
  }
}

// ---------------------------------------------------------------------------
// e_l[n,h] = sum_o Z[n,o,h]*a_l[o,h];  e_r likewise. One wave per node.
// ---------------------------------------------------------------------------
__global__ __launch_bounds__(256) void k_elr(const half_t* __restrict__ Zh,
                                             const float* __restrict__ al,
                                             const float* __restrict__ ar,
                                             float* __restrict__ el,
                                             float* __restrict__ er, int N) {
  int wid = threadIdx.x >> 6, lane = threadIdx.x & 63;
  int n = blockIdx.x * 4 + wid;
  if (n >= N) return;
  f16x8 z = *(const f16x8*)(Zh + (size_t)n * OH + lane * 8);
  const float4* ap = (const float4*)(al + lane * 8);
  float4 a0 = ap[0], a1 = ap[1];
  const float4* bp = (const float4*)(ar + lane * 8);
  float4 b0 = bp[0], b1 = bp[1];
  float zf[8];
#pragma unroll
  for (int j = 0; j < 8; j++) zf[j] = (float)z[j];

  float pl[8] = {zf[0] * a0.x, zf[1] * a0.y, zf[2] * a0.z, zf[3] * a0.w,
                 zf[4] * a1.x, zf[5] * a1.y, zf[6] * a1.z, zf[7] * a1.w};
  float pr[8] = {zf[0] * b0.x, zf[1] * b0.y, zf[2] * b0.z, zf[3] * b0.w,
                 zf[4] * b1.x, zf[5] * b1.y, zf[6] * b1.z, zf[7] * b1.w};
#pragma unroll
  for (int s = 1; s < 64; s <<= 1) {
#pragma unroll
    for (int h = 0; h < 8; h++) {
      pl[h] += __shfl_xor(pl[h], s);
      pr[h] += __shfl_xor(pr[h], s);
    }
  }
  if (lane == 0) {
    float4* e0 = (float4*)(el + (size_t)n * NH);
    e0[0] = make_float4(pl[0], pl[1], pl[2], pl[3]);
    e0[1] = make_float4(pl[4], pl[5], pl[6], pl[7]);
    float4* e1 = (float4*)(er + (size_t)n * NH);
    e1[0] = make_float4(pr[0], pr[1], pr[2], pr[3]);
    e1[1] = make_float4(pr[4], pr[5], pr[6], pr[7]);
  }
}

// ---------------------------------------------------------------------------
// CSR build
// ---------------------------------------------------------------------------
__global__ void k_zero(int* __restrict__ p, int n) {
  int i = blockIdx.x * blockDim.x + threadIdx.x;
  if (i < n) p[i] = 0;
}

__global__ void k_hist(const int* __restrict__ row, int* __restrict__ deg, int E) {
  int e = blockIdx.x * blockDim.x + threadIdx.x;
  if (e < E) atomicAdd(&deg[row[e]], 1);
}

#define SCAN_B 1024
__global__ __launch_bounds__(SCAN_B) void k_scan1(const int* __restrict__ deg,
                                                  int* __restrict__ off,
                                                  int* __restrict__ sums, int N) {
  __shared__ int s[SCAN_B];
  int tid = threadIdx.x;
  int g = blockIdx.x * SCAN_B + tid;
  int v = (g < N) ? deg[g] : 0;
  s[tid] = v;
  __syncthreads();
  for (int o = 1; o < SCAN_B; o <<= 1) {
    int t = (tid >= o) ? s[tid - o] : 0;
    __syncthreads();
    s[tid] += t;
    __syncthreads();
  }
  if (g < N) off[g] = s[tid] - v;
  if (tid == SCAN_B - 1) sums[blockIdx.x] = s[tid];
}

__global__ void k_scan2(const int* __restrict__ sums, int* __restrict__ boff,
                        int* __restrict__ off, int nb, int N, int E) {
  if (threadIdx.x == 0 && blockIdx.x == 0) {
    int run = 0;
    for (int b = 0; b < nb; ++b) { boff[b] = run; run += sums[b]; }
    off[N] = E;
  }
}

__global__ __launch_bounds__(SCAN_B) void k_scan3(int* __restrict__ off,
                                                  int* __restrict__ cursor,
                                                  const int* __restrict__ boff, int N) {
  int g = blockIdx.x * SCAN_B + threadIdx.x;
  if (g < N) {
    int v = off[g] + boff[blockIdx.x];
    off[g] = v;
    cursor[g] = v;
  }
}

__global__ void k_fill(const int* __restrict__ row, const int* __restrict__ col,
                       int* __restrict__ cursor, int* __restrict__ colS, int E) {
  int e = blockIdx.x * blockDim.x + threadIdx.x;
  if (e < E) {
    int r = row[e];
    int p = atomicAdd(&cursor[r], 1);
    colS[p] = col[e];
  }
}

// ---------------------------------------------------------------------------
// Fused edge-softmax + aggregation.  One wave per destination node.
// Phase A (lanes parallel over edges): per-edge logits -> wave max -> exp,
//   per-wave LDS stash of {col, w[8]} per edge (64-edge chunks).
// Phase B (all lanes cooperate per edge): acc[h] += w[h] * Zh[c][lane*8+h],
//   unrolled x4 for memory-level parallelism.
// Wave-synchronous: each wave uses only its own LDS slice -> no barriers.
// ---------------------------------------------------------------------------
__global__ __launch_bounds__(256) void k_attagg(const half_t* __restrict__ Zh,
                                                const float* __restrict__ el,
                                                const float* __restrict__ er,
                                                const int* __restrict__ off,
                                                const int* __restrict__ colS,
                                                float* __restrict__ out, int N) {
  __shared__ float wts[4][64][NH];   // 8 KB
  __shared__ int   cls[4][64];       // 1 KB
  int wid = threadIdx.x >> 6, lane = threadIdx.x & 63;
  int i = blockIdx.x * 4 + wid;
  if (i >= N) return;
  int s = off[i], t = off[i + 1];
  int deg = t - s;

  float eli[8];
  {
    const float4* e4 = (const float4*)(el + (size_t)i * NH);
    float4 a = e4[0], b = e4[1];
    eli[0] = a.x; eli[1] = a.y; eli[2] = a.z; eli[3] = a.w;
    eli[4] = b.x; eli[5] = b.y; eli[6] = b.z; eli[7] = b.w;
  }

  // ---- pass 1: per-edge logits, wave max (register-cache for deg<=64)
  float m[8], ehs[8];
  int csave = 0;
#pragma unroll
  for (int h = 0; h < 8; h++) m[h] = -1e30f;
  for (int p = s + lane; p < t; p += 64) {
    int c = colS[p];
    csave = c;
    const float4* e4 = (const float4*)(er + (size_t)c * NH);
    float4 ea = e4[0], eb = e4[1];
    float ev[8] = {ea.x, ea.y, ea.z, ea.w, eb.x, eb.y, eb.z, eb.w};
#pragma unroll
    for (int h = 0; h < 8; h++) {
      float eh = eli[h] + ev[h];
      eh = (eh > 0.f) ? eh : 0.01f * eh;
      ehs[h] = eh;                 // valid reuse iff deg<=64 (<=1 edge/lane)
      m[h] = fmaxf(m[h], eh);
    }
  }
#pragma unroll
  for (int st = 1; st < 64; st <<= 1)
#pragma unroll
    for (int h = 0; h < 8; h++) m[h] = fmaxf(m[h], __shfl_xor(m[h], st));

  float acc[8], den[8];
#pragma unroll
  for (int h = 0; h < 8; h++) { acc[h] = 0.f; den[h] = 0.f; }

  // ---- chunks of 64 edges: weights -> LDS, then cooperative gather
  for (int base = s; base < t; base += 64) {
    int p = base + lane;
    if (p < t) {
      int c;
      float eh[8];
      if (deg <= 64) {
        c = csave;
#pragma unroll
        for (int h = 0; h < 8; h++) eh[h] = ehs[h];
      } else {
        c = colS[p];
        const float4* e4 = (const float4*)(er + (size_t)c * NH);
        float4 ea = e4[0], eb = e4[1];
        float ev[8] = {ea.x, ea.y, ea.z, ea.w, eb.x, eb.y, eb.z, eb.w};
#pragma unroll
        for (int h = 0; h < 8; h++) {
          float e2 = eli[h] + ev[h];
          eh[h] = (e2 > 0.f) ? e2 : 0.01f * e2;
        }
      }
      cls[wid][lane] = c;
#pragma unroll
      for (int h = 0; h < 8; h++) {
        float pr = __expf(eh[h] - m[h]);
        den[h] += pr;
        wts[wid][lane][h] = pr;
      }
    }
    int cnt = t - base; if (cnt > 64) cnt = 64;

    int e = 0;
    for (; e + 4 <= cnt; e += 4) {
      int c0 = cls[wid][e + 0], c1 = cls[wid][e + 1];
      int c2 = cls[wid][e + 2], c3 = cls[wid][e + 3];
      f16x8 z0 = *(const f16x8*)(Zh + (size_t)c0 * OH + lane * 8);
      f16x8 z1 = *(const f16x8*)(Zh + (size_t)c1 * OH + lane * 8);
      f16x8 z2 = *(const f16x8*)(Zh + (size_t)c2 * OH + lane * 8);
      f16x8 z3 = *(const f16x8*)(Zh + (size_t)c3 * OH + lane * 8);
      const float* w0 = &wts[wid][e + 0][0];
      const float* w1 = &wts[wid][e + 1][0];
      const float* w2 = &wts[wid][e + 2][0];
      const float* w3 = &wts[wid][e + 3][0];
#pragma unroll
      for (int h = 0; h < 8; h++) {
        acc[h] = fmaf(w0[h], (float)z0[h], acc[h]);
        acc[h] = fmaf(w1[h], (float)z1[h], acc[h]);
        acc[h] = fmaf(w2[h], (float)z2[h], acc[h]);
        acc[h] = fmaf(w3[h], (float)z3[h], acc[h]);
      }
    }
    for (; e < cnt; e++) {
      int c = cls[wid][e];
      f16x8 z = *(const f16x8*)(Zh + (size_t)c * OH + lane * 8);
      const float* w = &wts[wid][e][0];
#pragma unroll
      for (int h = 0; h < 8; h++) acc[h] = fmaf(w[h], (float)z[h], acc[h]);
    }
  }

  // ---- denominator reduce + write
#pragma unroll
  for (int st = 1; st < 64; st <<= 1)
#pragma unroll
    for (int h = 0; h < 8; h++) den[h] += __shfl_xor(den[h], st);

  float4 o0 = make_float4(acc[0] / den[0], acc[1] / den[1],
                          acc[2] / den[2], acc[3] / den[3]);
  float4 o1 = make_float4(acc[4] / den[4], acc[5] / den[5],
                          acc[6] / den[6], acc[7] / den[7]);
  *(float4*)(out + (size_t)i * OH + lane * 8)     = o0;
  *(float4*)(out + (size_t)i * OH + lane * 8 + 4) = o1;
}

// ---------------------------------------------------------------------------
extern "C" void kernel_launch(void* const* d_in, const int* in_sizes, int n_in,
                              void* d_out, int out_size, void* d_ws, size_t ws_size,
                              hipStream_t stream) {
  const float* X    = (const float*)d_in[0];
  const float* W    = (const float*)d_in[1];
  const float* bias = (const float*)d_in[2];
  const float* a_l  = (const float*)d_in[3];
  const float* a_r  = (const float*)d_in[4];
  const int*   row  = (const int*)d_in[5];
  const int*   col  = (const int*)d_in[6];
  float* out = (float*)d_out;

  const int N = in_sizes[0] / IN_F;   // 50000
  const int E = in_sizes[5];          // 850000
  const size_t nX = (size_t)N * IN_F;
  const size_t nW = (size_t)OH * IN_F;

  auto align_up = [](size_t v) { return (v + 255) & ~(size_t)255; };
  char* p = (char*)d_ws;
  half_t* Xh    = (half_t*)p; p += align_up(nX * 2);
  half_t* Wh    = (half_t*)p; p += align_up(nW * 2);
  half_t* Zh    = (half_t*)p; p += align_up((size_t)N * OH * 2);
  float* el     = (float*)p;  p += align_up((size_t)N * NH * 4);
  float* er     = (float*)p;  p += align_up((size_t)N * NH * 4);
  int*   deg    = (int*)p;    p += align_up((size_t)N * 4);
  int*   off    = (int*)p;    p += align_up((size_t)(N + 1) * 4);
  int*   cursor = (int*)p;    p += align_up((size_t)N * 4);
  int*   sums   = (int*)p;    p += align_up((size_t)64 * 4);
  int*   boff   = (int*)p;    p += align_up((size_t)64 * 4);
  int*   colS   = (int*)p;    p += align_up((size_t)E * 4);
  (void)ws_size; (void)n_in; (void)out_size;

  const int nb = (N + SCAN_B - 1) / SCAN_B;

  // cast X, W to f16
  size_t nTot8 = (nX + nW) / 8;
  hipLaunchKernelGGL(k_cast, dim3((nTot8 + 255) / 256), dim3(256), 0, stream,
                     X, Xh, nX, W, Wh, nW);

  // MFMA GEMM  Zh = f16(X @ W^T + b)
  dim3 ggrid(OH / 128, (N + 127) / 128);
  hipLaunchKernelGGL(k_gemm16, ggrid, dim3(256), 0, stream, Xh, Wh, bias, Zh, N);

  // attention logit halves
  hipLaunchKernelGGL(k_elr, dim3((N + 3) / 4), dim3(256), 0, stream,
                     Zh, a_l, a_r, el, er, N);

  // CSR build
  hipLaunchKernelGGL(k_zero, dim3((N + 255) / 256), dim3(256), 0, stream, deg, N);
  hipLaunchKernelGGL(k_hist, dim3((E + 255) / 256), dim3(256), 0, stream, row, deg, E);
  hipLaunchKernelGGL(k_scan1, dim3(nb), dim3(SCAN_B), 0, stream, deg, off, sums, N);
  hipLaunchKernelGGL(k_scan2, dim3(1), dim3(64), 0, stream, sums, boff, off, nb, N, E);
  hipLaunchKernelGGL(k_scan3, dim3(nb), dim3(SCAN_B), 0, stream, off, cursor, boff, N);
  hipLaunchKernelGGL(k_fill, dim3((E + 255) / 256), dim3(256), 0, stream,
                     row, col, cursor, colS, E);

  // fused softmax + aggregation
  hipLaunchKernelGGL(k_attagg, dim3((N + 3) / 4), dim3(256), 0, stream,
                     Zh, el, er, off, colS, out, N);
}

// Round 5
// 366.987 us; speedup vs baseline: 2.1637x; 1.0520x over previous
//
#include <hip/hip_runtime.h>
#include <hip/hip_fp16.h>

#define IN_F 512
#define OH   512   // OUT*H
#define NH   8     // heads

typedef _Float16 half_t;
typedef __attribute__((ext_vector_type(8))) _Float16 f16x8;
typedef __attribute__((ext_vector_type(4))) float    f32x4;

#define GLOBAL_AS const __attribute__((address_space(1))) void
#define LDS_AS    __attribute__((address_space(3))) void

__device__ static inline void gload_lds16(const void* g, void* l) {
  __builtin_amdgcn_global_load_lds((GLOBAL_AS*)g, (LDS_AS*)l, 16, 0, 0);
}

// ---------------------------------------------------------------------------
// cast f32 -> f16 for W only (X cast is fused into the GEMM staging)
// ---------------------------------------------------------------------------
__global__ __launch_bounds__(256) void k_castW(const float* __restrict__ W,
                                               half_t* __restrict__ Wh, int n) {
  int i = (blockIdx.x * 256 + threadIdx.x) * 8;
  if (i >= n) return;
  float4 a = *(const float4*)(W + i);
  float4 b = *(const float4*)(W + i + 4);
  f16x8 h;
  h[0] = (half_t)a.x; h[1] = (half_t)a.y; h[2] = (half_t)a.z; h[3] = (half_t)a.w;
  h[4] = (half_t)b.x; h[5] = (half_t)b.y; h[6] = (half_t)b.z; h[7] = (half_t)b.w;
  *(f16x8*)(Wh + i) = h;
}

// ---------------------------------------------------------------------------
// MFMA f16 GEMM + fused cast(X) + fused el/er epilogue.
// Zh[n,j] = f16(sum_k X[n,k]*Wh[j,k] + bias[j])
// el[n]  += sum_j Z[n,j]*al[j]   (atomic, per 128-col block)
// 128x128 tile, BK=32, 4 waves (2x2). A: f32 load -> cvt -> ds_write.
// B: global_load_lds from Wh. 1-D grid with bijective XCD swizzle so the
// 4 col-blocks of one row-panel run consecutively on one XCD (X L2 reuse).
// ---------------------------------------------------------------------------
__global__ __launch_bounds__(256) void k_gemm16(const float* __restrict__ X,
                                                const half_t* __restrict__ Wh,
                                                const float* __restrict__ bias,
                                                const float* __restrict__ al,
                                                const float* __restrict__ ar,
                                                half_t* __restrict__ Zh,
                                                float* __restrict__ el,
                                                float* __restrict__ er,
                                                int N, int nwg) {
  __shared__ half_t smem[2][128][32];   // [0]=A tile, [1]=B tile (8KB each)
  const int tid  = threadIdx.x;
  const int lane = tid & 63;
  const int wid  = tid >> 6;
  const int wr = wid >> 1, wc = wid & 1;

  // bijective XCD swizzle (m204): xcd = orig & 7 on MI355X round-robin
  int orig = blockIdx.x;
  int xcd = orig & 7;
  int q = nwg >> 3, r = nwg & 7;
  int start = (xcd < r) ? xcd * (q + 1) : r * (q + 1) + (xcd - r) * q;
  int work = start + (orig >> 3);
  const int n0 = (work >> 2) * 128;
  const int j0 = (work & 3) * 128;

  f32x4 acc[4][4] = {};

  const int rl = lane & 15;
  const int kg = (lane >> 4) * 8;   // k-offset within BK: 0,8,16,24

  // A-staging indices: thread t -> row t>>1, 16-float segment (t&1)*16
  const int arow = tid >> 1;
  const int acol = (tid & 1) * 16;
  int an = n0 + arow; if (an > N - 1) an = N - 1;
  const float* xrow = X + (size_t)an * IN_F + acol;

  for (int kt = 0; kt < IN_F; kt += 32) {
    // ---- A: f32 global -> cvt f16 -> LDS
    float4 f0 = *(const float4*)(xrow + kt);
    float4 f1 = *(const float4*)(xrow + kt + 4);
    float4 f2 = *(const float4*)(xrow + kt + 8);
    float4 f3 = *(const float4*)(xrow + kt + 12);
    f16x8 h0, h1;
    h0[0] = (half_t)f0.x; h0[1] = (half_t)f0.y; h0[2] = (half_t)f0.z; h0[3] = (half_t)f0.w;
    h0[4] = (half_t)f1.x; h0[5] = (half_t)f1.y; h0[6] = (half_t)f1.z; h0[7] = (half_t)f1.w;
    h1[0] = (half_t)f2.x; h1[1] = (half_t)f2.y; h1[2] = (half_t)f2.z; h1[3] = (half_t)f2.w;
    h1[4] = (half_t)f3.x; h1[5] = (half_t)f3.y; h1[6] = (half_t)f3.z; h1[7] = (half_t)f3.w;
    *(f16x8*)&smem[0][arow][acol]     = h0;
    *(f16x8*)&smem[0][arow][acol + 8] = h1;

    // ---- B: 8KB via global_load_lds (wave wid owns bytes [wid*2K, wid*2K+2K))
#pragma unroll
    for (int c = 0; c < 2; c++) {
      int o = wid * 2048 + c * 1024 + lane * 16;  // linear byte in B region
      int brow = o >> 6;
      int bcolh = (o & 63) >> 1;
      const half_t* g = Wh + (size_t)(j0 + brow) * IN_F + kt + bcolh;
      char* l = (char*)&smem[1][0][0] + wid * 2048 + c * 1024;
      gload_lds16(g, l);
    }
    __syncthreads();   // drains lgkmcnt (ds_write) + vmcnt (gload_lds)

    f16x8 af[4], bf[4];
#pragma unroll
    for (int m = 0; m < 4; m++)
      af[m] = *(const f16x8*)&smem[0][wr * 64 + m * 16 + rl][kg];
#pragma unroll
    for (int n = 0; n < 4; n++)
      bf[n] = *(const f16x8*)&smem[1][wc * 64 + n * 16 + rl][kg];

#pragma unroll
    for (int m = 0; m < 4; m++)
#pragma unroll
      for (int n = 0; n < 4; n++)
        acc[m][n] = __builtin_amdgcn_mfma_f32_16x16x32_f16(af[m], bf[n], acc[m][n], 0, 0, 0);
    __syncthreads();
  }

  // ---- epilogue: Zh write + el/er partials.
  // C/D layout: col=lane&15, row=(lane>>4)*4+q
  float partl[4][4], partr[4][4];
#pragma unroll
  for (int m = 0; m < 4; m++)
#pragma unroll
    for (int qq = 0; qq < 4; qq++) { partl[m][qq] = 0.f; partr[m][qq] = 0.f; }

#pragma unroll
  for (int n = 0; n < 4; n++) {
    int j = j0 + wc * 64 + n * 16 + rl;
    float bv = bias[j];
    float av = al[j];
    float rv = ar[j];
#pragma unroll
    for (int m = 0; m < 4; m++) {
      int rbase = n0 + wr * 64 + m * 16 + (lane >> 4) * 4;
#pragma unroll
      for (int qq = 0; qq < 4; qq++) {
        float v = acc[m][n][qq] + bv;
        int nrow = rbase + qq;
        if (nrow < N) Zh[(size_t)nrow * OH + j] = (half_t)v;
        partl[m][qq] = fmaf(v, av, partl[m][qq]);
        partr[m][qq] = fmaf(v, rv, partr[m][qq]);
      }
    }
  }
  // reduce over the 16 j-lanes (rl), then one atomic per row per wave
#pragma unroll
  for (int m = 0; m < 4; m++) {
#pragma unroll
    for (int qq = 0; qq < 4; qq++) {
      float pl = partl[m][qq], pr = partr[m][qq];
#pragma unroll
      for (int s = 1; s < 16; s <<= 1) {
        pl += __shfl_xor(pl, s);
        pr += __shfl_xor(pr, s);
      }
      if (rl == 0) {
        int nrow = n0 + wr * 64 + m * 16 + (lane >> 4) * 4 + qq;
        if (nrow < N) {
          atomicAdd(&el[(size_t)nrow * NH + 0], 0.f);  // keep address calc simple
          // el/er are [N][NH] but the reduction above is over j = o*8+h for
          // ALL h in this wave's 64 cols -> j covers 8*o+h; al[j] weighting
          // already folds h. el here is el_flat[n*8+h]? NO: we accumulated
          // over all j in the block, mixing heads. See note below.
        }
      }
    }
  }
}

// NOTE: the mixed-head reduction above is WRONG -- el[n,h] must stay per-head.
// Corrected epilogue is in k_gemm16_v2 below; k_gemm16 is unused.

// ---------------------------------------------------------------------------
// Corrected GEMM: el/er per-head. j = o*8 + h, h = j & 7. Within the 16-lane
// rl-group, lanes rl and rl+8 share h (j differs by 64 -> same h). Reducing
// with xor masks {8} merges o-pairs with same h; masks {1,2,4} mix heads.
// So: reduce over rl with xor 8 only (pairs), then each lane rl in 0..7 holds
// the h=(j&7) partial summed over 2 o-values x 4 n = 8 of the 16 o's in this
// wave's 64 cols... Simpler correct scheme: accumulate per-head in registers
// directly: for fixed (m,qq,h) sum over the n and the two rl-positions with
// that h. Implemented below via per-head atomics from each lane (rl<8 after
// one xor-8 fold): 8 atomics per (m,qq) per wave -> 512 per block. Fine.
// ---------------------------------------------------------------------------
__global__ __launch_bounds__(256) void k_gemm16_v2(const float* __restrict__ X,
                                                   const half_t* __restrict__ Wh,
                                                   const float* __restrict__ bias,
                                                   const float* __restrict__ al,
                                                   const float* __restrict__ ar,
                                                   half_t* __restrict__ Zh,
                                                   float* __restrict__ el,
                                                   float* __restrict__ er,
                                                   int N, int nwg) {
  __shared__ half_t smem[2][128][32];
  const int tid  = threadIdx.x;
  const int lane = tid & 63;
  const int wid  = tid >> 6;
  const int wr = wid >> 1, wc = wid & 1;

  int orig = blockIdx.x;
  int xcd = orig & 7;
  int q = nwg >> 3, r = nwg & 7;
  int start = (xcd < r) ? xcd * (q + 1) : r * (q + 1) + (xcd - r) * q;
  int work = start + (orig >> 3);
  const int n0 = (work >> 2) * 128;
  const int j0 = (work & 3) * 128;

  f32x4 acc[4][4] = {};

  const int rl = lane & 15;
  const int kg = (lane >> 4) * 8;

  const int arow = tid >> 1;
  const int acol = (tid & 1) * 16;
  int an = n0 + arow; if (an > N - 1) an = N - 1;
  const float* xrow = X + (size_t)an * IN_F + acol;

  for (int kt = 0; kt < IN_F; kt += 32) {
    float4 f0 = *(const float4*)(xrow + kt);
    float4 f1 = *(const float4*)(xrow + kt + 4);
    float4 f2 = *(const float4*)(xrow + kt + 8);
    float4 f3 = *(const float4*)(xrow + kt + 12);
    f16x8 h0, h1;
    h0[0] = (half_t)f0.x; h0[1] = (half_t)f0.y; h0[2] = (half_t)f0.z; h0[3] = (half_t)f0.w;
    h0[4] = (half_t)f1.x; h0[5] = (half_t)f1.y; h0[6] = (half_t)f1.z; h0[7] = (half_t)f1.w;
    h1[0] = (half_t)f2.x; h1[1] = (half_t)f2.y; h1[2] = (half_t)f2.z; h1[3] = (half_t)f2.w;
    h1[4] = (half_t)f3.x; h1[5] = (half_t)f3.y; h1[6] = (half_t)f3.z; h1[7] = (half_t)f3.w;
    *(f16x8*)&smem[0][arow][acol]     = h0;
    *(f16x8*)&smem[0][arow][acol + 8] = h1;

#pragma unroll
    for (int c = 0; c < 2; c++) {
      int o = wid * 2048 + c * 1024 + lane * 16;
      int brow = o >> 6;
      int bcolh = (o & 63) >> 1;
      const half_t* g = Wh + (size_t)(j0 + brow) * IN_F + kt + bcolh;
      char* l = (char*)&smem[1][0][0] + wid * 2048 + c * 1024;
      gload_lds16(g, l);
    }
    __syncthreads();

    f16x8 af[4], bf[4];
#pragma unroll
    for (int m = 0; m < 4; m++)
      af[m] = *(const f16x8*)&smem[0][wr * 64 + m * 16 + rl][kg];
#pragma unroll
    for (int n = 0; n < 4; n++)
      bf[n] = *(const f16x8*)&smem[1][wc * 64 + n * 16 + rl][kg];

#pragma unroll
    for (int m = 0; m < 4; m++)
#pragma unroll
      for (int n = 0; n < 4; n++)
        acc[m][n] = __builtin_amdgcn_mfma_f32_16x16x32_f16(af[m], bf[n], acc[m][n], 0, 0, 0);
    __syncthreads();
  }

  // epilogue: Zh write + per-head el/er partials.
  // lane's head h = j & 7 = rl & 7 (same for all n since 16 | strides).
  float partl[4][4], partr[4][4];
#pragma unroll
  for (int m = 0; m < 4; m++)
#pragma unroll
    for (int qq = 0; qq < 4; qq++) { partl[m][qq] = 0.f; partr[m][qq] = 0.f; }

#pragma unroll
  for (int n = 0; n < 4; n++) {
    int j = j0 + wc * 64 + n * 16 + rl;
    float bv = bias[j];
    float av = al[j];
    float rv = ar[j];
#pragma unroll
    for (int m = 0; m < 4; m++) {
      int rbase = n0 + wr * 64 + m * 16 + (lane >> 4) * 4;
#pragma unroll
      for (int qq = 0; qq < 4; qq++) {
        float v = acc[m][n][qq] + bv;
        int nrow = rbase + qq;
        if (nrow < N) Zh[(size_t)nrow * OH + j] = (half_t)v;
        partl[m][qq] = fmaf(v, av, partl[m][qq]);
        partr[m][qq] = fmaf(v, rv, partr[m][qq]);
      }
    }
  }
  const int h = rl & 7;   // head of this lane's partials
#pragma unroll
  for (int m = 0; m < 4; m++) {
#pragma unroll
    for (int qq = 0; qq < 4; qq++) {
      float pl = partl[m][qq], pr = partr[m][qq];
      // fold rl and rl+8 (same head, different o): xor 8
      pl += __shfl_xor(pl, 8);
      pr += __shfl_xor(pr, 8);
      if (rl < 8) {
        int nrow = n0 + wr * 64 + m * 16 + (lane >> 4) * 4 + qq;
        if (nrow < N) {
          atomicAdd(&el[(size_t)nrow * NH + h], pl);
          atomicAdd(&er[(size_t)nrow * NH + h], pr);
        }
      }
    }
  }
}

// ---------------------------------------------------------------------------
// CSR build
// ---------------------------------------------------------------------------
__global__ void k_hist(const int* __restrict__ row, int* __restrict__ deg, int E) {
  int e = blockIdx.x * blockDim.x + threadIdx.x;
  if (e < E) atomicAdd(&deg[row[e]], 1);
}

#define SCAN_B 1024
__global__ __launch_bounds__(SCAN_B) void k_scan1(const int* __restrict__ deg,
                                                  int* __restrict__ off,
                                                  int* __restrict__ sums, int N) {
  __shared__ int s[SCAN_B];
  int tid = threadIdx.x;
  int g = blockIdx.x * SCAN_B + tid;
  int v = (g < N) ? deg[g] : 0;
  s[tid] = v;
  __syncthreads();
  for (int o = 1; o < SCAN_B; o <<= 1) {
    int t = (tid >= o) ? s[tid - o] : 0;
    __syncthreads();
    s[tid] += t;
    __syncthreads();
  }
  if (g < N) off[g] = s[tid] - v;
  if (tid == SCAN_B - 1) sums[blockIdx.x] = s[tid];
}

// scan3 with fused block-offset computation (nb <= 64)
__global__ __launch_bounds__(SCAN_B) void k_scan3(int* __restrict__ off,
                                                  int* __restrict__ cursor,
                                                  const int* __restrict__ sums,
                                                  int nb, int N, int E) {
  __shared__ int sboff;
  int tid = threadIdx.x;
  if (tid < 64) {
    int v = (tid < nb && tid < (int)blockIdx.x) ? sums[tid] : 0;
#pragma unroll
    for (int s = 1; s < 64; s <<= 1) v += __shfl_xor(v, s);
    if (tid == 0) sboff = v;
  }
  __syncthreads();
  int g = blockIdx.x * SCAN_B + tid;
  if (g < N) {
    int v = off[g] + sboff;
    off[g] = v;
    cursor[g] = v;
  }
  if (g == 0) off[N] = E;
}

__global__ void k_fill(const int* __restrict__ row, const int* __restrict__ col,
                       int* __restrict__ cursor, int* __restrict__ colS, int E) {
  int e = blockIdx.x * blockDim.x + threadIdx.x;
  if (e < E) {
    int r = row[e];
    int p = atomicAdd(&cursor[r], 1);
    colS[p] = col[e];
  }
}

// ---------------------------------------------------------------------------
// Fused edge-softmax + aggregation (unchanged from round 4 -- at fabric floor)
// ---------------------------------------------------------------------------
__global__ __launch_bounds__(256) void k_attagg(const half_t* __restrict__ Zh,
                                                const float* __restrict__ el,
                                                const float* __restrict__ er,
                                                const int* __restrict__ off,
                                                const int* __restrict__ colS,
                                                float* __restrict__ out, int N) {
  __shared__ float wts[4][64][NH];   // 8 KB
  __shared__ int   cls[4][64];       // 1 KB
  int wid = threadIdx.x >> 6, lane = threadIdx.x & 63;
  int i = blockIdx.x * 4 + wid;
  if (i >= N) return;
  int s = off[i], t = off[i + 1];
  int deg = t - s;

  float eli[8];
  {
    const float4* e4 = (const float4*)(el + (size_t)i * NH);
    float4 a = e4[0], b = e4[1];
    eli[0] = a.x; eli[1] = a.y; eli[2] = a.z; eli[3] = a.w;
    eli[4] = b.x; eli[5] = b.y; eli[6] = b.z; eli[7] = b.w;
  }

  float m[8], ehs[8];
  int csave = 0;
#pragma unroll
  for (int h = 0; h < 8; h++) m[h] = -1e30f;
  for (int p = s + lane; p < t; p += 64) {
    int c = colS[p];
    csave = c;
    const float4* e4 = (const float4*)(er + (size_t)c * NH);
    float4 ea = e4[0], eb = e4[1];
    float ev[8] = {ea.x, ea.y, ea.z, ea.w, eb.x, eb.y, eb.z, eb.w};
#pragma unroll
    for (int h = 0; h < 8; h++) {
      float eh = eli[h] + ev[h];
      eh = (eh > 0.f) ? eh : 0.01f * eh;
      ehs[h] = eh;
      m[h] = fmaxf(m[h], eh);
    }
  }
#pragma unroll
  for (int st = 1; st < 64; st <<= 1)
#pragma unroll
    for (int h = 0; h < 8; h++) m[h] = fmaxf(m[h], __shfl_xor(m[h], st));

  float acc[8], den[8];
#pragma unroll
  for (int h = 0; h < 8; h++) { acc[h] = 0.f; den[h] = 0.f; }

  for (int base = s; base < t; base += 64) {
    int p = base + lane;
    if (p < t) {
      int c;
      float eh[8];
      if (deg <= 64) {
        c = csave;
#pragma unroll
        for (int h = 0; h < 8; h++) eh[h] = ehs[h];
      } else {
        c = colS[p];
        const float4* e4 = (const float4*)(er + (size_t)c * NH);
        float4 ea = e4[0], eb = e4[1];
        float ev[8] = {ea.x, ea.y, ea.z, ea.w, eb.x, eb.y, eb.z, eb.w};
#pragma unroll
        for (int h = 0; h < 8; h++) {
          float e2 = eli[h] + ev[h];
          eh[h] = (e2 > 0.f) ? e2 : 0.01f * e2;
        }
      }
      cls[wid][lane] = c;
#pragma unroll
      for (int h = 0; h < 8; h++) {
        float pr = __expf(eh[h] - m[h]);
        den[h] += pr;
        wts[wid][lane][h] = pr;
      }
    }
    int cnt = t - base; if (cnt > 64) cnt = 64;

    int e = 0;
    for (; e + 4 <= cnt; e += 4) {
      int c0 = cls[wid][e + 0], c1 = cls[wid][e + 1];
      int c2 = cls[wid][e + 2], c3 = cls[wid][e + 3];
      f16x8 z0 = *(const f16x8*)(Zh + (size_t)c0 * OH + lane * 8);
      f16x8 z1 = *(const f16x8*)(Zh + (size_t)c1 * OH + lane * 8);
      f16x8 z2 = *(const f16x8*)(Zh + (size_t)c2 * OH + lane * 8);
      f16x8 z3 = *(const f16x8*)(Zh + (size_t)c3 * OH + lane * 8);
      const float* w0 = &wts[wid][e + 0][0];
      const float* w1 = &wts[wid][e + 1][0];
      const float* w2 = &wts[wid][e + 2][0];
      const float* w3 = &wts[wid][e + 3][0];
#pragma unroll
      for (int h = 0; h < 8; h++) {
        acc[h] = fmaf(w0[h], (float)z0[h], acc[h]);
        acc[h] = fmaf(w1[h], (float)z1[h], acc[h]);
        acc[h] = fmaf(w2[h], (float)z2[h], acc[h]);
        acc[h] = fmaf(w3[h], (float)z3[h], acc[h]);
      }
    }
    for (; e < cnt; e++) {
      int c = cls[wid][e];
      f16x8 z = *(const f16x8*)(Zh + (size_t)c * OH + lane * 8);
      const float* w = &wts[wid][e][0];
#pragma unroll
      for (int h = 0; h < 8; h++) acc[h] = fmaf(w[h], (float)z[h], acc[h]);
    }
  }

#pragma unroll
  for (int st = 1; st < 64; st <<= 1)
#pragma unroll
    for (int h = 0; h < 8; h++) den[h] += __shfl_xor(den[h], st);

  float4 o0 = make_float4(acc[0] / den[0], acc[1] / den[1],
                          acc[2] / den[2], acc[3] / den[3]);
  float4 o1 = make_float4(acc[4] / den[4], acc[5] / den[5],
                          acc[6] / den[6], acc[7] / den[7]);
  *(float4*)(out + (size_t)i * OH + lane * 8)     = o0;
  *(float4*)(out + (size_t)i * OH + lane * 8 + 4) = o1;
}

// ---------------------------------------------------------------------------
extern "C" void kernel_launch(void* const* d_in, const int* in_sizes, int n_in,
                              void* d_out, int out_size, void* d_ws, size_t ws_size,
                              hipStream_t stream) {
  const float* X    = (const float*)d_in[0];
  const float* W    = (const float*)d_in[1];
  const float* bias = (const float*)d_in[2];
  const float* a_l  = (const float*)d_in[3];
  const float* a_r  = (const float*)d_in[4];
  const int*   row  = (const int*)d_in[5];
  const int*   col  = (const int*)d_in[6];
  float* out = (float*)d_out;

  const int N = in_sizes[0] / IN_F;   // 50000
  const int E = in_sizes[5];          // 850000
  const int nWe = OH * IN_F;          // W element count

  auto align_up = [](size_t v) { return (v + 255) & ~(size_t)255; };
  char* p = (char*)d_ws;
  half_t* Wh    = (half_t*)p; p += align_up((size_t)nWe * 2);
  half_t* Zh    = (half_t*)p; p += align_up((size_t)N * OH * 2);
  float* el     = (float*)p;  p += (size_t)N * NH * 4;        // keep el/er contiguous
  float* er     = (float*)p;  p += align_up((size_t)N * NH * 4);
  int*   deg    = (int*)p;    p += align_up((size_t)N * 4);
  int*   off    = (int*)p;    p += align_up((size_t)(N + 1) * 4);
  int*   cursor = (int*)p;    p += align_up((size_t)N * 4);
  int*   sums   = (int*)p;    p += align_up((size_t)64 * 4);
  int*   colS   = (int*)p;    p += align_up((size_t)E * 4);
  (void)ws_size; (void)n_in; (void)out_size;

  const int nb = (N + SCAN_B - 1) / SCAN_B;

  // zero-init deg and el/er (contiguous)
  hipMemsetAsync(deg, 0, (size_t)N * 4, stream);
  hipMemsetAsync(el, 0, (size_t)2 * N * NH * 4, stream);

  // cast W to f16
  hipLaunchKernelGGL(k_castW, dim3((nWe / 8 + 255) / 256), dim3(256), 0, stream,
                     W, Wh, nWe);

  // fused cast(X) + MFMA GEMM + el/er epilogue
  const int nwg = ((N + 127) / 128) * 4;
  hipLaunchKernelGGL(k_gemm16_v2, dim3(nwg), dim3(256), 0, stream,
                     X, Wh, bias, a_l, a_r, Zh, el, er, N, nwg);

  // CSR build
  hipLaunchKernelGGL(k_hist, dim3((E + 255) / 256), dim3(256), 0, stream, row, deg, E);
  hipLaunchKernelGGL(k_scan1, dim3(nb), dim3(SCAN_B), 0, stream, deg, off, sums, N);
  hipLaunchKernelGGL(k_scan3, dim3(nb), dim3(SCAN_B), 0, stream,
                     off, cursor, sums, nb, N, E);
  hipLaunchKernelGGL(k_fill, dim3((E + 255) / 256), dim3(256), 0, stream,
                     row, col, cursor, colS, E);

  // fused softmax + aggregation
  hipLaunchKernelGGL(k_attagg, dim3((N + 3) / 4), dim3(256), 0, stream,
                     Zh, el, er, off, colS, out, N);
}

// Round 6
// 338.621 us; speedup vs baseline: 2.3449x; 1.0838x over previous
//
#include <hip/hip_runtime.h>
#include <hip/hip_fp16.h>

#define IN_F 512
#define OH   512   // OUT*H
#define NH   8     // heads

typedef _Float16 half_t;
typedef __attribute__((ext_vector_type(8))) _Float16 f16x8;
typedef __attribute__((ext_vector_type(4))) float    f32x4;

#define GLOBAL_AS const __attribute__((address_space(1))) void
#define LDS_AS    __attribute__((address_space(3))) void

__device__ static inline void gload_lds16(const void* g, void* l) {
  __builtin_amdgcn_global_load_lds((GLOBAL_AS*)g, (LDS_AS*)l, 16, 0, 0);
}

// ---------------------------------------------------------------------------
// cast f32 -> f16 for W only (1 MB -> 0.5 MB, ~3 us)
// ---------------------------------------------------------------------------
__global__ __launch_bounds__(256) void k_castW(const float* __restrict__ W,
                                               half_t* __restrict__ Wh, int n) {
  int i = (blockIdx.x * 256 + threadIdx.x) * 8;
  if (i >= n) return;
  float4 a = *(const float4*)(W + i);
  float4 b = *(const float4*)(W + i + 4);
  f16x8 h;
  h[0] = (half_t)a.x; h[1] = (half_t)a.y; h[2] = (half_t)a.z; h[3] = (half_t)a.w;
  h[4] = (half_t)b.x; h[5] = (half_t)b.y; h[6] = (half_t)b.z; h[7] = (half_t)b.w;
  *(f16x8*)(Wh + i) = h;
}

// ---------------------------------------------------------------------------
// MFMA f16 GEMM, 2-phase double-buffered pipeline (T3/T4 minimal recipe):
//   prologue: STAGE(buf0, kt=0)
//   iter ki:  STAGE(buf^1, kt+32); s_waitcnt vmcnt(6); s_barrier;
//             ds_read frags(buf) + 16 MFMA; s_barrier
// A is staged f32 directly from X via global_load_lds with a granule XOR
// swizzle (pre-swizzled GLOBAL source + swizzled ds_read; LDS dest linear —
// rule #21).  Row of A = 32 f32 = 8 granules of 16B; granule sg holds global
// granule sg^(row&7).  Fragment reads then hit 8 distinct bank groups
// (2-way aliasing = free) instead of 16-way.
// B staged f16 linear from Wh (m97 layout, proven fine).
// Epilogue: Zh write + fused per-head el/er atomic partials.
// ---------------------------------------------------------------------------
__global__ __launch_bounds__(256) void k_gemm16_v3(const float* __restrict__ X,
                                                   const half_t* __restrict__ Wh,
                                                   const float* __restrict__ bias,
                                                   const float* __restrict__ al,
                                                   const float* __restrict__ ar,
                                                   half_t* __restrict__ Zh,
                                                   float* __restrict__ el,
                                                   float* __restrict__ er,
                                                   int N, int nwg) {
  __shared__ float  As[2][128][32];   // 2 x 16 KB
  __shared__ half_t Bs[2][128][32];   // 2 x 8 KB
  const int tid  = threadIdx.x;
  const int lane = tid & 63;
  const int wid  = tid >> 6;
  const int wr = wid >> 1, wc = wid & 1;

  // bijective XCD swizzle (m204)
  int orig = blockIdx.x;
  int xcd = orig & 7;
  int q = nwg >> 3, r = nwg & 7;
  int start = (xcd < r) ? xcd * (q + 1) : r * (q + 1) + (xcd - r) * q;
  int work = start + (orig >> 3);
  const int n0 = (work >> 2) * 128;
  const int j0 = (work & 3) * 128;

  f32x4 acc[4][4] = {};

  const int rl = lane & 15;
  const int hi16 = lane >> 4;
  const int kg = hi16 * 8;      // k-offset (halves/floats) within BK=32

  // ---- precompute per-lane staging sources (kt-invariant parts) ----
  // A: wave stages LDS bytes [wid*4096, +4096) of As[buf]; HW dest = base+lane*16.
  //    lane's chunk c covers byte off = wid*4096 + c*1024 + lane*16.
  int a_row[4], a_gsg[4];
#pragma unroll
  for (int c = 0; c < 4; c++) {
    int off = wid * 4096 + c * 1024 + lane * 16;
    int row = off >> 7;                 // 0..127
    int sg  = (off >> 4) & 7;           // granule within row
    a_row[c] = row;
    a_gsg[c] = sg ^ (row & 7);          // pre-swizzled global granule
  }
  // B: wave stages LDS bytes [wid*2048, +2048) of Bs[buf]
  int b_row[2], b_colh[2];
#pragma unroll
  for (int c = 0; c < 2; c++) {
    int off = wid * 2048 + c * 1024 + lane * 16;
    b_row[c]  = off >> 6;
    b_colh[c] = (off >> 1) & 31;
  }

#define STAGE(BUF, KT)                                                         \
  do {                                                                         \
    _Pragma("unroll")                                                          \
    for (int c = 0; c < 4; c++) {                                              \
      int an = n0 + a_row[c]; if (an >= N) an = N - 1;                         \
      const float* g = X + (size_t)an * IN_F + (KT) + a_gsg[c] * 4;            \
      gload_lds16(g, (char*)&As[BUF][0][0] + wid * 4096 + c * 1024);           \
    }                                                                          \
    _Pragma("unroll")                                                          \
    for (int c = 0; c < 2; c++) {                                              \
      const half_t* g = Wh + (size_t)(j0 + b_row[c]) * IN_F + (KT) + b_colh[c];\
      gload_lds16(g, (char*)&Bs[BUF][0][0] + wid * 2048 + c * 1024);           \
    }                                                                          \
  } while (0)

  STAGE(0, 0);

#pragma unroll
  for (int ki = 0; ki < IN_F / 32; ki++) {
    const int cur = ki & 1;
    if (ki < IN_F / 32 - 1) {
      STAGE(cur ^ 1, (ki + 1) * 32);
      asm volatile("s_waitcnt vmcnt(6)" ::: "memory");  // prev tile done, next in flight
    } else {
      asm volatile("s_waitcnt vmcnt(0)" ::: "memory");
    }
    __builtin_amdgcn_s_barrier();

    // ---- fragments ----
    f16x8 af[4], bf[4];
#pragma unroll
    for (int m = 0; m < 4; m++) {
      int row = wr * 64 + m * 16 + rl;
      int r7 = row & 7;
      int ga = hi16 * 2;                 // lo granule (global)
      const char* base = (const char*)&As[cur][row][0];
      f32x4 lo = *(const f32x4*)(base + ((ga ^ r7) << 4));
      f32x4 hi = *(const f32x4*)(base + (((ga + 1) ^ r7) << 4));
      f16x8 a;
#pragma unroll
      for (int u = 0; u < 4; u++) { a[u] = (half_t)lo[u]; a[u + 4] = (half_t)hi[u]; }
      af[m] = a;
    }
#pragma unroll
    for (int n = 0; n < 4; n++)
      bf[n] = *(const f16x8*)&Bs[cur][wc * 64 + n * 16 + rl][kg];

#pragma unroll
    for (int m = 0; m < 4; m++)
#pragma unroll
      for (int n = 0; n < 4; n++)
        acc[m][n] = __builtin_amdgcn_mfma_f32_16x16x32_f16(af[m], bf[n], acc[m][n], 0, 0, 0);

    __builtin_amdgcn_s_barrier();   // reads of buf[cur] done before it is re-staged
  }
#undef STAGE

  // ---- epilogue: Zh write + per-head el/er partials ----
  // C/D layout: col=lane&15, row=(lane>>4)*4+q.  Lane's head h = rl & 7.
  float partl[4][4], partr[4][4];
#pragma unroll
  for (int m = 0; m < 4; m++)
#pragma unroll
    for (int qq = 0; qq < 4; qq++) { partl[m][qq] = 0.f; partr[m][qq] = 0.f; }

#pragma unroll
  for (int n = 0; n < 4; n++) {
    int j = j0 + wc * 64 + n * 16 + rl;
    float bv = bias[j];
    float av = al[j];
    float rv = ar[j];
#pragma unroll
    for (int m = 0; m < 4; m++) {
      int rbase = n0 + wr * 64 + m * 16 + hi16 * 4;
#pragma unroll
      for (int qq = 0; qq < 4; qq++) {
        float v = acc[m][n][qq] + bv;
        int nrow = rbase + qq;
        if (nrow < N) Zh[(size_t)nrow * OH + j] = (half_t)v;
        partl[m][qq] = fmaf(v, av, partl[m][qq]);
        partr[m][qq] = fmaf(v, rv, partr[m][qq]);
      }
    }
  }
  const int h = rl & 7;
#pragma unroll
  for (int m = 0; m < 4; m++) {
#pragma unroll
    for (int qq = 0; qq < 4; qq++) {
      float pl = partl[m][qq], pr = partr[m][qq];
      pl += __shfl_xor(pl, 8);    // fold rl and rl+8 (same head)
      pr += __shfl_xor(pr, 8);
      if (rl < 8) {
        int nrow = n0 + wr * 64 + m * 16 + hi16 * 4 + qq;
        if (nrow < N) {
          atomicAdd(&el[(size_t)nrow * NH + h], pl);
          atomicAdd(&er[(size_t)nrow * NH + h], pr);
        }
      }
    }
  }
}

// ---------------------------------------------------------------------------
// CSR build
// ---------------------------------------------------------------------------
__global__ void k_hist(const int* __restrict__ row, int* __restrict__ deg, int E) {
  int e = blockIdx.x * blockDim.x + threadIdx.x;
  if (e < E) atomicAdd(&deg[row[e]], 1);
}

#define SCAN_B 1024
__global__ __launch_bounds__(SCAN_B) void k_scan1(const int* __restrict__ deg,
                                                  int* __restrict__ off,
                                                  int* __restrict__ sums, int N) {
  __shared__ int s[SCAN_B];
  int tid = threadIdx.x;
  int g = blockIdx.x * SCAN_B + tid;
  int v = (g < N) ? deg[g] : 0;
  s[tid] = v;
  __syncthreads();
  for (int o = 1; o < SCAN_B; o <<= 1) {
    int t = (tid >= o) ? s[tid - o] : 0;
    __syncthreads();
    s[tid] += t;
    __syncthreads();
  }
  if (g < N) off[g] = s[tid] - v;
  if (tid == SCAN_B - 1) sums[blockIdx.x] = s[tid];
}

__global__ __launch_bounds__(SCAN_B) void k_scan3(int* __restrict__ off,
                                                  int* __restrict__ cursor,
                                                  const int* __restrict__ sums,
                                                  int nb, int N, int E) {
  __shared__ int sboff;
  int tid = threadIdx.x;
  if (tid < 64) {
    int v = (tid < nb && tid < (int)blockIdx.x) ? sums[tid] : 0;
#pragma unroll
    for (int s = 1; s < 64; s <<= 1) v += __shfl_xor(v, s);
    if (tid == 0) sboff = v;
  }
  __syncthreads();
  int g = blockIdx.x * SCAN_B + tid;
  if (g < N) {
    int v = off[g] + sboff;
    off[g] = v;
    cursor[g] = v;
  }
  if (g == 0) off[N] = E;
}

__global__ void k_fill(const int* __restrict__ row, const int* __restrict__ col,
                       int* __restrict__ cursor, int* __restrict__ colS, int E) {
  int e = blockIdx.x * blockDim.x + threadIdx.x;
  if (e < E) {
    int r = row[e];
    int p = atomicAdd(&cursor[r], 1);
    colS[p] = col[e];
  }
}

// ---------------------------------------------------------------------------
// Fused edge-softmax + aggregation (unchanged -- at fabric floor)
// ---------------------------------------------------------------------------
__global__ __launch_bounds__(256) void k_attagg(const half_t* __restrict__ Zh,
                                                const float* __restrict__ el,
                                                const float* __restrict__ er,
                                                const int* __restrict__ off,
                                                const int* __restrict__ colS,
                                                float* __restrict__ out, int N) {
  __shared__ float wts[4][64][NH];   // 8 KB
  __shared__ int   cls[4][64];       // 1 KB
  int wid = threadIdx.x >> 6, lane = threadIdx.x & 63;
  int i = blockIdx.x * 4 + wid;
  if (i >= N) return;
  int s = off[i], t = off[i + 1];
  int deg = t - s;

  float eli[8];
  {
    const float4* e4 = (const float4*)(el + (size_t)i * NH);
    float4 a = e4[0], b = e4[1];
    eli[0] = a.x; eli[1] = a.y; eli[2] = a.z; eli[3] = a.w;
    eli[4] = b.x; eli[5] = b.y; eli[6] = b.z; eli[7] = b.w;
  }

  float m[8], ehs[8];
  int csave = 0;
#pragma unroll
  for (int h = 0; h < 8; h++) m[h] = -1e30f;
  for (int p = s + lane; p < t; p += 64) {
    int c = colS[p];
    csave = c;
    const float4* e4 = (const float4*)(er + (size_t)c * NH);
    float4 ea = e4[0], eb = e4[1];
    float ev[8] = {ea.x, ea.y, ea.z, ea.w, eb.x, eb.y, eb.z, eb.w};
#pragma unroll
    for (int h = 0; h < 8; h++) {
      float eh = eli[h] + ev[h];
      eh = (eh > 0.f) ? eh : 0.01f * eh;
      ehs[h] = eh;
      m[h] = fmaxf(m[h], eh);
    }
  }
#pragma unroll
  for (int st = 1; st < 64; st <<= 1)
#pragma unroll
    for (int h = 0; h < 8; h++) m[h] = fmaxf(m[h], __shfl_xor(m[h], st));

  float acc[8], den[8];
#pragma unroll
  for (int h = 0; h < 8; h++) { acc[h] = 0.f; den[h] = 0.f; }

  for (int base = s; base < t; base += 64) {
    int p = base + lane;
    if (p < t) {
      int c;
      float eh[8];
      if (deg <= 64) {
        c = csave;
#pragma unroll
        for (int h = 0; h < 8; h++) eh[h] = ehs[h];
      } else {
        c = colS[p];
        const float4* e4 = (const float4*)(er + (size_t)c * NH);
        float4 ea = e4[0], eb = e4[1];
        float ev[8] = {ea.x, ea.y, ea.z, ea.w, eb.x, eb.y, eb.z, eb.w};
#pragma unroll
        for (int h = 0; h < 8; h++) {
          float e2 = eli[h] + ev[h];
          eh[h] = (e2 > 0.f) ? e2 : 0.01f * e2;
        }
      }
      cls[wid][lane] = c;
#pragma unroll
      for (int h = 0; h < 8; h++) {
        float pr = __expf(eh[h] - m[h]);
        den[h] += pr;
        wts[wid][lane][h] = pr;
      }
    }
    int cnt = t - base; if (cnt > 64) cnt = 64;

    int e = 0;
    for (; e + 4 <= cnt; e += 4) {
      int c0 = cls[wid][e + 0], c1 = cls[wid][e + 1];
      int c2 = cls[wid][e + 2], c3 = cls[wid][e + 3];
      f16x8 z0 = *(const f16x8*)(Zh + (size_t)c0 * OH + lane * 8);
      f16x8 z1 = *(const f16x8*)(Zh + (size_t)c1 * OH + lane * 8);
      f16x8 z2 = *(const f16x8*)(Zh + (size_t)c2 * OH + lane * 8);
      f16x8 z3 = *(const f16x8*)(Zh + (size_t)c3 * OH + lane * 8);
      const float* w0 = &wts[wid][e + 0][0];
      const float* w1 = &wts[wid][e + 1][0];
      const float* w2 = &wts[wid][e + 2][0];
      const float* w3 = &wts[wid][e + 3][0];
#pragma unroll
      for (int h = 0; h < 8; h++) {
        acc[h] = fmaf(w0[h], (float)z0[h], acc[h]);
        acc[h] = fmaf(w1[h], (float)z1[h], acc[h]);
        acc[h] = fmaf(w2[h], (float)z2[h], acc[h]);
        acc[h] = fmaf(w3[h], (float)z3[h], acc[h]);
      }
    }
    for (; e < cnt; e++) {
      int c = cls[wid][e];
      f16x8 z = *(const f16x8*)(Zh + (size_t)c * OH + lane * 8);
      const float* w = &wts[wid][e][0];
#pragma unroll
      for (int h = 0; h < 8; h++) acc[h] = fmaf(w[h], (float)z[h], acc[h]);
    }
  }

#pragma unroll
  for (int st = 1; st < 64; st <<= 1)
#pragma unroll
    for (int h = 0; h < 8; h++) den[h] += __shfl_xor(den[h], st);

  float4 o0 = make_float4(acc[0] / den[0], acc[1] / den[1],
                          acc[2] / den[2], acc[3] / den[3]);
  float4 o1 = make_float4(acc[4] / den[4], acc[5] / den[5],
                          acc[6] / den[6], acc[7] / den[7]);
  *(float4*)(out + (size_t)i * OH + lane * 8)     = o0;
  *(float4*)(out + (size_t)i * OH + lane * 8 + 4) = o1;
}

// ---------------------------------------------------------------------------
extern "C" void kernel_launch(void* const* d_in, const int* in_sizes, int n_in,
                              void* d_out, int out_size, void* d_ws, size_t ws_size,
                              hipStream_t stream) {
  const float* X    = (const float*)d_in[0];
  const float* W    = (const float*)d_in[1];
  const float* bias = (const float*)d_in[2];
  const float* a_l  = (const float*)d_in[3];
  const float* a_r  = (const float*)d_in[4];
  const int*   row  = (const int*)d_in[5];
  const int*   col  = (const int*)d_in[6];
  float* out = (float*)d_out;

  const int N = in_sizes[0] / IN_F;   // 50000
  const int E = in_sizes[5];          // 850000
  const int nWe = OH * IN_F;

  auto align_up = [](size_t v) { return (v + 255) & ~(size_t)255; };
  char* p = (char*)d_ws;
  half_t* Wh    = (half_t*)p; p += align_up((size_t)nWe * 2);
  half_t* Zh    = (half_t*)p; p += align_up((size_t)N * OH * 2);
  float* el     = (float*)p;  p += (size_t)N * NH * 4;        // el/er contiguous
  float* er     = (float*)p;  p += align_up((size_t)N * NH * 4);
  int*   deg    = (int*)p;    p += align_up((size_t)N * 4);
  int*   off    = (int*)p;    p += align_up((size_t)(N + 1) * 4);
  int*   cursor = (int*)p;    p += align_up((size_t)N * 4);
  int*   sums   = (int*)p;    p += align_up((size_t)64 * 4);
  int*   colS   = (int*)p;    p += align_up((size_t)E * 4);
  (void)ws_size; (void)n_in; (void)out_size;

  const int nb = (N + SCAN_B - 1) / SCAN_B;

  hipMemsetAsync(deg, 0, (size_t)N * 4, stream);
  hipMemsetAsync(el, 0, (size_t)2 * N * NH * 4, stream);

  hipLaunchKernelGGL(k_castW, dim3((nWe / 8 + 255) / 256), dim3(256), 0, stream,
                     W, Wh, nWe);

  // pipelined MFMA GEMM (fused X-cast via f32 LDS staging) + el/er epilogue
  const int nwg = ((N + 127) / 128) * 4;
  hipLaunchKernelGGL(k_gemm16_v3, dim3(nwg), dim3(256), 0, stream,
                     X, Wh, bias, a_l, a_r, Zh, el, er, N, nwg);

  // CSR build
  hipLaunchKernelGGL(k_hist, dim3((E + 255) / 256), dim3(256), 0, stream, row, deg, E);
  hipLaunchKernelGGL(k_scan1, dim3(nb), dim3(SCAN_B), 0, stream, deg, off, sums, N);
  hipLaunchKernelGGL(k_scan3, dim3(nb), dim3(SCAN_B), 0, stream,
                     off, cursor, sums, nb, N, E);
  hipLaunchKernelGGL(k_fill, dim3((E + 255) / 256), dim3(256), 0, stream,
                     row, col, cursor, colS, E);

  // fused softmax + aggregation
  hipLaunchKernelGGL(k_attagg, dim3((N + 3) / 4), dim3(256), 0, stream,
                     Zh, el, er, off, colS, out, N);
}